// Round 1
// baseline (1651.033 us; speedup 1.0000x reference)
//
#include <hip/hip_runtime.h>

#define TSEQ 2048
#define NHEAD 16
#define DM 1024
#define NBATCH 2
#define MTOK (NBATCH * TSEQ)   // 4096

// ---------------------------------------------------------------------------
// GEMM: C[M,N] = A[M,K] @ B[N,K]^T  with M=4096, N=1024, K=1024 (row-major).
// Tile 128x64, BK=16, 256 threads, 8x4 micro-tile per thread.
// ---------------------------------------------------------------------------
__global__ __launch_bounds__(256)
void gemm_abt_kernel(const float* __restrict__ A, const float* __restrict__ B,
                     float* __restrict__ C)
{
    constexpr int K = 1024, N = 1024;
    __shared__ __align__(16) float As[16][132];  // [k][m], pad 132 (16B-aligned rows)
    __shared__ __align__(16) float Bs[16][68];   // [k][n], pad 68

    const int t   = threadIdx.x;
    const int ty  = t >> 4;          // 0..15 -> rows 8*ty..8*ty+7
    const int tx  = t & 15;          // 0..15 -> cols 4*tx..4*tx+3
    const int row0 = blockIdx.x * 128;
    const int col0 = blockIdx.y * 64;

    // staging map: A needs 128 rows x 4 float4-segs = 512 loads (2/thread),
    // B needs 64 rows x 4 segs = 256 loads (1/thread)
    const int lr  = t >> 2;          // 0..63
    const int ls  = t & 3;           // 0..3
    const float* Ap  = A + (size_t)(row0 + lr) * K + ls * 4;
    const float* Ap2 = Ap + (size_t)64 * K;
    const float* Bp  = B + (size_t)(col0 + lr) * K + ls * 4;

    float acc[8][4] = {};

    for (int k0 = 0; k0 < K; k0 += 16) {
        float4 av0 = *(const float4*)(Ap  + k0);
        float4 av1 = *(const float4*)(Ap2 + k0);
        float4 bv  = *(const float4*)(Bp  + k0);
        __syncthreads();   // previous iteration's LDS reads complete
        As[ls*4+0][lr]      = av0.x; As[ls*4+1][lr]      = av0.y;
        As[ls*4+2][lr]      = av0.z; As[ls*4+3][lr]      = av0.w;
        As[ls*4+0][lr+64]   = av1.x; As[ls*4+1][lr+64]   = av1.y;
        As[ls*4+2][lr+64]   = av1.z; As[ls*4+3][lr+64]   = av1.w;
        Bs[ls*4+0][lr]      = bv.x;  Bs[ls*4+1][lr]      = bv.y;
        Bs[ls*4+2][lr]      = bv.z;  Bs[ls*4+3][lr]      = bv.w;
        __syncthreads();
        #pragma unroll
        for (int kk = 0; kk < 16; ++kk) {
            float4 a0 = *(const float4*)&As[kk][ty*8];
            float4 a1 = *(const float4*)&As[kk][ty*8+4];
            float4 b  = *(const float4*)&Bs[kk][tx*4];
            float ar[8] = {a0.x,a0.y,a0.z,a0.w,a1.x,a1.y,a1.z,a1.w};
            float br[4] = {b.x,b.y,b.z,b.w};
            #pragma unroll
            for (int i = 0; i < 8; ++i)
                #pragma unroll
                for (int j = 0; j < 4; ++j)
                    acc[i][j] = fmaf(ar[i], br[j], acc[i][j]);
        }
    }
    #pragma unroll
    for (int i = 0; i < 8; ++i) {
        float4 o = make_float4(acc[i][0], acc[i][1], acc[i][2], acc[i][3]);
        *(float4*)&C[(size_t)(row0 + ty*8 + i) * N + col0 + tx*4] = o;
    }
}

// ---------------------------------------------------------------------------
// RoPE (in-place) on q,k,q2,k2. One thread per (b,t,h,pair-j); 4 tensors each.
// y1 = x1*cos + x2*sin ; y2 = -x1*sin + x2*cos  (reference convention)
// ---------------------------------------------------------------------------
__global__ __launch_bounds__(256)
void rope4_kernel(float* __restrict__ q, float* __restrict__ k,
                  float* __restrict__ q2, float* __restrict__ k2)
{
    int idx = blockIdx.x * 256 + threadIdx.x;      // 0 .. B*T*H*32-1
    int j    = idx & 31;                            // pair index
    int row  = idx >> 5;                            // (b*T + t)*H + h
    int tpos = (row >> 4) & (TSEQ - 1);             // t
    int base = row * 64 + j;

    float inv = powf(10000.0f, -(2.0f * (float)j) / 64.0f);
    float f = (float)tpos * inv;
    float c = cosf(f);
    float s = sinf(f);

    float* ptrs[4] = {q, k, q2, k2};
    #pragma unroll
    for (int p = 0; p < 4; ++p) {
        float x1 = ptrs[p][base];
        float x2 = ptrs[p][base + 32];
        ptrs[p][base]      = x1 * c + x2 * s;
        ptrs[p][base + 32] = x2 * c - x1 * s;
    }
}

// ---------------------------------------------------------------------------
// Bilinear causal attention. One block per (b, h, q-tile of 64).
// S1 = q.k^T, S2 = q2.k2^T over Dh=64; P = (S1*S2)/4096 masked; z += P.v
// LDS buffers [64 tok][64 d] with quad swizzle: col4' = col4 ^ ((row>>2)&15)
// kl is reused as the P buffer ([n][m], same swizzle on m).
// ---------------------------------------------------------------------------
__global__ __launch_bounds__(256)
void attn_kernel(const float* __restrict__ q,  const float* __restrict__ k,
                 const float* __restrict__ q2, const float* __restrict__ k2,
                 const float* __restrict__ v,  float* __restrict__ z)
{
    __shared__ __align__(16) float ql [64*64];
    __shared__ __align__(16) float q2l[64*64];
    __shared__ __align__(16) float kl [64*64];   // reused as P after S-phase
    __shared__ __align__(16) float k2l[64*64];
    __shared__ __align__(16) float vl [64*64];

    const int qt = gridDim.x - 1 - blockIdx.x;   // heavy (large qt) blocks first
    const int h  = blockIdx.y;
    const int b  = blockIdx.z;
    const int t  = threadIdx.x;
    const int ty = t >> 4;      // 0..15 : m rows 4*ty..
    const int tx = t & 15;      // 0..15 : n cols / d cols 4*tx..

    const size_t hb   = (size_t)h * 64;
    const size_t qoff = ((size_t)(b * TSEQ) + (size_t)qt * 64) * DM + hb;

    // stage q, q2 (once per block)
    {
        int tokl = t >> 4;      // 0..15
        int seg  = t & 15;
        #pragma unroll
        for (int r = 0; r < 4; ++r) {
            int tok = r * 16 + tokl;
            int la  = tok * 64 + ((seg ^ (tok >> 2)) << 2);
            *(float4*)&ql [la] = *(const float4*)(q  + qoff + (size_t)tok * DM + seg * 4);
            *(float4*)&q2l[la] = *(const float4*)(q2 + qoff + (size_t)tok * DM + seg * 4);
        }
    }

    float zacc[4][4] = {};
    const float scale = 1.0f / 4096.0f;

    for (int tk = 0; tk <= qt; ++tk) {
        const size_t kbase = ((size_t)(b * TSEQ) + (size_t)tk * 64) * DM + hb;
        // prefetch staging loads into registers before the barrier
        float4 kreg[4], k2reg[4], vreg[4];
        int la_s[4];
        {
            int tokl = t >> 4, seg = t & 15;
            #pragma unroll
            for (int r = 0; r < 4; ++r) {
                int tok = r * 16 + tokl;
                size_t g = kbase + (size_t)tok * DM + seg * 4;
                kreg[r]  = *(const float4*)(k  + g);
                k2reg[r] = *(const float4*)(k2 + g);
                vreg[r]  = *(const float4*)(v  + g);
                la_s[r]  = tok * 64 + ((seg ^ (tok >> 2)) << 2);
            }
        }
        __syncthreads();    // prev z-phase reads of kl(P)/vl complete
        #pragma unroll
        for (int r = 0; r < 4; ++r) {
            *(float4*)&kl [la_s[r]] = kreg[r];
            *(float4*)&k2l[la_s[r]] = k2reg[r];
            *(float4*)&vl [la_s[r]] = vreg[r];
        }
        __syncthreads();

        // ---- S-phase: S1, S2 (64x64 tile, 4x4 per thread, dot4 over d) ----
        float s1[4][4] = {}, s2[4][4] = {};
        #pragma unroll 2
        for (int c4 = 0; c4 < 16; ++c4) {
            float4 qa[4], qb[4], ka[4], kb[4];
            #pragma unroll
            for (int i = 0; i < 4; ++i) {
                int off = (4*ty + i) * 64 + ((c4 ^ ty) << 2);
                qa[i] = *(const float4*)&ql [off];
                qb[i] = *(const float4*)&q2l[off];
            }
            #pragma unroll
            for (int jj = 0; jj < 4; ++jj) {
                int off = (4*tx + jj) * 64 + ((c4 ^ tx) << 2);
                ka[jj] = *(const float4*)&kl [off];
                kb[jj] = *(const float4*)&k2l[off];
            }
            #pragma unroll
            for (int i = 0; i < 4; ++i)
                #pragma unroll
                for (int jj = 0; jj < 4; ++jj) {
                    s1[i][jj] = fmaf(qa[i].x, ka[jj].x, s1[i][jj]);
                    s1[i][jj] = fmaf(qa[i].y, ka[jj].y, s1[i][jj]);
                    s1[i][jj] = fmaf(qa[i].z, ka[jj].z, s1[i][jj]);
                    s1[i][jj] = fmaf(qa[i].w, ka[jj].w, s1[i][jj]);
                    s2[i][jj] = fmaf(qb[i].x, kb[jj].x, s2[i][jj]);
                    s2[i][jj] = fmaf(qb[i].y, kb[jj].y, s2[i][jj]);
                    s2[i][jj] = fmaf(qb[i].z, kb[jj].z, s2[i][jj]);
                    s2[i][jj] = fmaf(qb[i].w, kb[jj].w, s2[i][jj]);
                }
        }

        __syncthreads();    // all S-phase reads of kl done; safe to overwrite as P
        // ---- P = mask(S1*S2/4096), store to kl as [n][m] (swizzled m) ----
        #pragma unroll
        for (int jj = 0; jj < 4; ++jj) {
            int n    = 4*tx + jj;
            int ktok = tk*64 + n;
            int pb   = n * 64 + ((ty ^ tx) << 2);
            #pragma unroll
            for (int i = 0; i < 4; ++i) {
                int qtok = qt*64 + 4*ty + i;
                kl[pb + i] = (ktok <= qtok) ? s1[i][jj] * s2[i][jj] * scale : 0.0f;
            }
        }
        __syncthreads();

        // ---- z-phase: z[m][d] += P[m][n] * v[n][d] ----
        #pragma unroll 8
        for (int kk = 0; kk < 64; ++kk) {
            float4 a  = *(const float4*)&kl[kk * 64 + ((ty ^ (kk >> 2)) << 2)];
            float4 vv = *(const float4*)&vl[kk * 64 + ((tx ^ (kk >> 2)) << 2)];
            float av[4] = {a.x, a.y, a.z, a.w};
            float vw[4] = {vv.x, vv.y, vv.z, vv.w};
            #pragma unroll
            for (int i = 0; i < 4; ++i)
                #pragma unroll
                for (int jj = 0; jj < 4; ++jj)
                    zacc[i][jj] = fmaf(av[i], vw[jj], zacc[i][jj]);
        }
    }

    // write z[b][qtok][h][d]
    float* zg = z + qoff;
    #pragma unroll
    for (int i = 0; i < 4; ++i) {
        float4 o = make_float4(zacc[i][0], zacc[i][1], zacc[i][2], zacc[i][3]);
        *(float4*)&zg[(size_t)(4*ty + i) * DM + tx * 4] = o;
    }
}

// ---------------------------------------------------------------------------
extern "C" void kernel_launch(void* const* d_in, const int* in_sizes, int n_in,
                              void* d_out, int out_size, void* d_ws, size_t ws_size,
                              hipStream_t stream)
{
    const float* x     = (const float*)d_in[0];
    const float* Wq    = (const float*)d_in[1];
    const float* Wk    = (const float*)d_in[2];
    const float* Wq2   = (const float*)d_in[3];
    const float* Wk2   = (const float*)d_in[4];
    const float* Wv    = (const float*)d_in[5];
    const float* Wproj = (const float*)d_in[6];

    const size_t SZ = (size_t)MTOK * DM;   // 4096*1024 floats per tensor
    float* ws = (float*)d_ws;
    float* q  = ws;
    float* k  = ws + 1*SZ;
    float* q2 = ws + 2*SZ;
    float* k2 = ws + 3*SZ;
    float* v  = ws + 4*SZ;
    float* zb = ws + 5*SZ;

    dim3 ggrid(MTOK / 128, DM / 64);        // 32 x 16
    gemm_abt_kernel<<<ggrid, 256, 0, stream>>>(x, Wq,  q);
    gemm_abt_kernel<<<ggrid, 256, 0, stream>>>(x, Wk,  k);
    gemm_abt_kernel<<<ggrid, 256, 0, stream>>>(x, Wq2, q2);
    gemm_abt_kernel<<<ggrid, 256, 0, stream>>>(x, Wk2, k2);
    gemm_abt_kernel<<<ggrid, 256, 0, stream>>>(x, Wv,  v);

    int npairs = NBATCH * TSEQ * NHEAD * 32;   // 2,097,152
    rope4_kernel<<<npairs / 256, 256, 0, stream>>>(q, k, q2, k2);

    attn_kernel<<<dim3(TSEQ / 64, NHEAD, NBATCH), 256, 0, stream>>>(q, k, q2, k2, v, zb);

    gemm_abt_kernel<<<ggrid, 256, 0, stream>>>(zb, Wproj, (float*)d_out);
}

// Round 2
// 1196.453 us; speedup vs baseline: 1.3799x; 1.3799x over previous
//
#include <hip/hip_runtime.h>

#define TSEQ 2048
#define NHEAD 16
#define DM 1024
#define NBATCH 2
#define MTOK (NBATCH * TSEQ)   // 4096

typedef __attribute__((ext_vector_type(8))) short short8;
typedef __attribute__((ext_vector_type(4))) float floatx4;
typedef __attribute__((address_space(1))) const void gvoid;
typedef __attribute__((address_space(3))) void lvoid;

// ---------------------------------------------------------------------------
// Split fp32 -> packed bf16 [hi(1024) | lo(1024)] per row. 4 elems/thread.
// ---------------------------------------------------------------------------
static __device__ __forceinline__ unsigned short f2bf(float f) {
    unsigned int u = __float_as_uint(f);
    return (unsigned short)((u + 0x7fffu + ((u >> 16) & 1u)) >> 16);
}
static __device__ __forceinline__ float bf2f(unsigned short h) {
    return __uint_as_float(((unsigned int)h) << 16);
}

__global__ __launch_bounds__(256)
void pack_split_kernel(const float* __restrict__ src, unsigned short* __restrict__ dst)
{
    int gid = blockIdx.x * 256 + threadIdx.x;
    int e   = gid * 4;
    int row = e >> 10;
    int col = e & 1023;
    float4 f = *(const float4*)(src + (size_t)row * 1024 + col);
    ushort4 hi, lo;
    hi.x = f2bf(f.x); lo.x = f2bf(f.x - bf2f(hi.x));
    hi.y = f2bf(f.y); lo.y = f2bf(f.y - bf2f(hi.y));
    hi.z = f2bf(f.z); lo.z = f2bf(f.z - bf2f(hi.z));
    hi.w = f2bf(f.w); lo.w = f2bf(f.w - bf2f(hi.w));
    *(ushort4*)(dst + (size_t)row * 2048 + col)        = hi;
    *(ushort4*)(dst + (size_t)row * 2048 + 1024 + col) = lo;
}

// 6 weight matrices [1024][1024] -> Wp rows wi*1024.. ; wi = blockIdx.x>>10
__global__ __launch_bounds__(256)
void pack_split_w6_kernel(const float* __restrict__ w0, const float* __restrict__ w1,
                          const float* __restrict__ w2, const float* __restrict__ w3,
                          const float* __restrict__ w4, const float* __restrict__ w5,
                          unsigned short* __restrict__ dst)
{
    int wi  = blockIdx.x >> 10;
    const float* srcs[6] = {w0, w1, w2, w3, w4, w5};
    const float* src = srcs[wi];
    int gid = (blockIdx.x & 1023) * 256 + threadIdx.x;
    int e   = gid * 4;
    int row = e >> 10;
    int col = e & 1023;
    float4 f = *(const float4*)(src + (size_t)row * 1024 + col);
    ushort4 hi, lo;
    hi.x = f2bf(f.x); lo.x = f2bf(f.x - bf2f(hi.x));
    hi.y = f2bf(f.y); lo.y = f2bf(f.y - bf2f(hi.y));
    hi.z = f2bf(f.z); lo.z = f2bf(f.z - bf2f(hi.z));
    hi.w = f2bf(f.w); lo.w = f2bf(f.w - bf2f(hi.w));
    unsigned short* d = dst + (size_t)(wi * 1024 + row) * 2048;
    *(ushort4*)(d + col)        = hi;
    *(ushort4*)(d + 1024 + col) = lo;
}

// ---------------------------------------------------------------------------
// Split-bf16 GEMM: C[M][ldc] = A*B^T in fp32-like precision.
// Ap[M][2048] = [hi|lo], Bp[N][2048] = [hi|lo]. Virtual K = 3072:
//   A reads [hi|hi|lo]  (acol = k0<1024 ? k0 : k0-1024)
//   B reads [hi|lo|hi]  (bcol = k0<2048 ? k0 : k0-2048)
// => C = hiA.hiB + hiA.loB + loA.hiB  (drops loA.loB ~ 2^-16 rel)
// 128x128 tile, 256 thr = 4 waves (2x2 of 64x64), 16x16x32 bf16 MFMA,
// global_load_lds width 16, single-buffer 2-barrier K-loop (m97 structure).
// ---------------------------------------------------------------------------
__global__ __launch_bounds__(256)
void gemm_split_bf16(const unsigned short* __restrict__ Ap,
                     const unsigned short* __restrict__ Bp,
                     float* __restrict__ C, int ldc)
{
    __shared__ __align__(16) unsigned short As[128 * 32];
    __shared__ __align__(16) unsigned short Bs[128 * 32];

    const int t    = threadIdx.x;
    const int lane = t & 63;
    const int w    = t >> 6;
    const int row0 = blockIdx.x * 128;
    const int col0 = blockIdx.y * 128;
    const int m0   = (w >> 1) * 64;
    const int n0   = (w & 1) * 64;

    floatx4 acc[4][4];
    #pragma unroll
    for (int i = 0; i < 4; ++i)
        #pragma unroll
        for (int j = 0; j < 4; ++j)
            acc[i][j] = (floatx4)(0.0f);

    // staging map: thread t stages 8 bf16 at row (t>>2), kofs (t&3)*8; issue j adds 64 rows
    const int sr = t >> 2;
    const int sk = (t & 3) * 8;
    char* ldsA = (char*)As + (size_t)t * 16;
    char* ldsB = (char*)Bs + (size_t)t * 16;
    const size_t arow = (size_t)(row0 + sr) * 2048 + sk;
    const size_t brow = (size_t)(col0 + sr) * 2048 + sk;

    #define ISSUE(k0)                                                                     \
    {                                                                                     \
        int acol = ((k0) < 1024) ? (k0) : (k0) - 1024;                                    \
        int bcol = ((k0) < 2048) ? (k0) : (k0) - 2048;                                    \
        const unsigned short* ga = Ap + arow + acol;                                      \
        const unsigned short* gb = Bp + brow + bcol;                                      \
        __builtin_amdgcn_global_load_lds((gvoid*)ga,              (lvoid*)ldsA,        16, 0, 0); \
        __builtin_amdgcn_global_load_lds((gvoid*)(ga + 64*2048),  (lvoid*)(ldsA+4096), 16, 0, 0); \
        __builtin_amdgcn_global_load_lds((gvoid*)gb,              (lvoid*)ldsB,        16, 0, 0); \
        __builtin_amdgcn_global_load_lds((gvoid*)(gb + 64*2048),  (lvoid*)(ldsB+4096), 16, 0, 0); \
    }

    ISSUE(0);
    for (int ks = 0; ks < 96; ++ks) {
        __syncthreads();   // drains vmcnt: staged tile visible to all
        short8 af[4], bfr[4];
        #pragma unroll
        for (int i = 0; i < 4; ++i) {
            af[i]  = *(const short8*)&As[(m0 + i * 16 + (lane & 15)) * 32 + (lane >> 4) * 8];
            bfr[i] = *(const short8*)&Bs[(n0 + i * 16 + (lane & 15)) * 32 + (lane >> 4) * 8];
        }
        #pragma unroll
        for (int i = 0; i < 4; ++i)
            #pragma unroll
            for (int j = 0; j < 4; ++j)
                acc[i][j] = __builtin_amdgcn_mfma_f32_16x16x32_bf16(af[i], bfr[j], acc[i][j], 0, 0, 0);
        __syncthreads();   // all LDS reads done; safe to overwrite
        if (ks + 1 < 96) {
            int k0 = (ks + 1) * 32;
            ISSUE(k0);
        }
    }
    #undef ISSUE

    // C/D layout: col = lane&15, row = (lane>>4)*4 + reg
    const int cr = (lane >> 4) * 4;
    const int cc = lane & 15;
    #pragma unroll
    for (int i = 0; i < 4; ++i)
        #pragma unroll
        for (int j = 0; j < 4; ++j) {
            int r = row0 + m0 + i * 16 + cr;
            int c = col0 + n0 + j * 16 + cc;
            #pragma unroll
            for (int rr = 0; rr < 4; ++rr)
                C[(size_t)(r + rr) * ldc + c] = acc[i][j][rr];
        }
}

// ---------------------------------------------------------------------------
// RoPE (in-place) on q,k,q2,k2 living in qkv[4096][5120] at col ofs 0/1024/2048/3072
// ---------------------------------------------------------------------------
__global__ __launch_bounds__(256)
void rope4_kernel(float* __restrict__ qkv)
{
    int idx  = blockIdx.x * 256 + threadIdx.x;     // 0 .. B*T*H*32-1
    int j    = idx & 31;
    int row  = idx >> 5;                            // rowtok*16 + h
    int tpos = (row >> 4) & (TSEQ - 1);
    int base = (row >> 4) * 5120 + (row & 15) * 64 + j;

    float inv = powf(10000.0f, -(2.0f * (float)j) / 64.0f);
    float f = (float)tpos * inv;
    float c = cosf(f);
    float s = sinf(f);

    #pragma unroll
    for (int p = 0; p < 4; ++p) {
        float* ptr = qkv + p * 1024;
        float x1 = ptr[base];
        float x2 = ptr[base + 32];
        ptr[base]      = x1 * c + x2 * s;
        ptr[base + 32] = x2 * c - x1 * s;
    }
}

// ---------------------------------------------------------------------------
// Bilinear causal attention (fp32, unchanged logic; input row stride ldin).
// ---------------------------------------------------------------------------
__global__ __launch_bounds__(256)
void attn_kernel(const float* __restrict__ q,  const float* __restrict__ k,
                 const float* __restrict__ q2, const float* __restrict__ k2,
                 const float* __restrict__ v,  float* __restrict__ z, int ldin)
{
    __shared__ __align__(16) float ql [64*64];
    __shared__ __align__(16) float q2l[64*64];
    __shared__ __align__(16) float kl [64*64];   // reused as P after S-phase
    __shared__ __align__(16) float k2l[64*64];
    __shared__ __align__(16) float vl [64*64];

    const int qt = gridDim.x - 1 - blockIdx.x;
    const int h  = blockIdx.y;
    const int b  = blockIdx.z;
    const int t  = threadIdx.x;
    const int ty = t >> 4;
    const int tx = t & 15;

    const size_t hb   = (size_t)h * 64;
    const size_t qoff = ((size_t)(b * TSEQ) + (size_t)qt * 64) * ldin + hb;

    {
        int tokl = t >> 4;
        int seg  = t & 15;
        #pragma unroll
        for (int r = 0; r < 4; ++r) {
            int tok = r * 16 + tokl;
            int la  = tok * 64 + ((seg ^ (tok >> 2)) << 2);
            *(float4*)&ql [la] = *(const float4*)(q  + qoff + (size_t)tok * ldin + seg * 4);
            *(float4*)&q2l[la] = *(const float4*)(q2 + qoff + (size_t)tok * ldin + seg * 4);
        }
    }

    float zacc[4][4] = {};
    const float scale = 1.0f / 4096.0f;

    for (int tk = 0; tk <= qt; ++tk) {
        const size_t kbase = ((size_t)(b * TSEQ) + (size_t)tk * 64) * ldin + hb;
        float4 kreg[4], k2reg[4], vreg[4];
        int la_s[4];
        {
            int tokl = t >> 4, seg = t & 15;
            #pragma unroll
            for (int r = 0; r < 4; ++r) {
                int tok = r * 16 + tokl;
                size_t g = kbase + (size_t)tok * ldin + seg * 4;
                kreg[r]  = *(const float4*)(k  + g);
                k2reg[r] = *(const float4*)(k2 + g);
                vreg[r]  = *(const float4*)(v  + g);
                la_s[r]  = tok * 64 + ((seg ^ (tok >> 2)) << 2);
            }
        }
        __syncthreads();
        #pragma unroll
        for (int r = 0; r < 4; ++r) {
            *(float4*)&kl [la_s[r]] = kreg[r];
            *(float4*)&k2l[la_s[r]] = k2reg[r];
            *(float4*)&vl [la_s[r]] = vreg[r];
        }
        __syncthreads();

        float s1[4][4] = {}, s2[4][4] = {};
        #pragma unroll 2
        for (int c4 = 0; c4 < 16; ++c4) {
            float4 qa[4], qb[4], ka[4], kb[4];
            #pragma unroll
            for (int i = 0; i < 4; ++i) {
                int off = (4*ty + i) * 64 + ((c4 ^ ty) << 2);
                qa[i] = *(const float4*)&ql [off];
                qb[i] = *(const float4*)&q2l[off];
            }
            #pragma unroll
            for (int jj = 0; jj < 4; ++jj) {
                int off = (4*tx + jj) * 64 + ((c4 ^ tx) << 2);
                ka[jj] = *(const float4*)&kl [off];
                kb[jj] = *(const float4*)&k2l[off];
            }
            #pragma unroll
            for (int i = 0; i < 4; ++i)
                #pragma unroll
                for (int jj = 0; jj < 4; ++jj) {
                    s1[i][jj] = fmaf(qa[i].x, ka[jj].x, s1[i][jj]);
                    s1[i][jj] = fmaf(qa[i].y, ka[jj].y, s1[i][jj]);
                    s1[i][jj] = fmaf(qa[i].z, ka[jj].z, s1[i][jj]);
                    s1[i][jj] = fmaf(qa[i].w, ka[jj].w, s1[i][jj]);
                    s2[i][jj] = fmaf(qb[i].x, kb[jj].x, s2[i][jj]);
                    s2[i][jj] = fmaf(qb[i].y, kb[jj].y, s2[i][jj]);
                    s2[i][jj] = fmaf(qb[i].z, kb[jj].z, s2[i][jj]);
                    s2[i][jj] = fmaf(qb[i].w, kb[jj].w, s2[i][jj]);
                }
        }

        __syncthreads();
        #pragma unroll
        for (int jj = 0; jj < 4; ++jj) {
            int n    = 4*tx + jj;
            int ktok = tk*64 + n;
            int pb   = n * 64 + ((ty ^ tx) << 2);
            #pragma unroll
            for (int i = 0; i < 4; ++i) {
                int qtok = qt*64 + 4*ty + i;
                kl[pb + i] = (ktok <= qtok) ? s1[i][jj] * s2[i][jj] * scale : 0.0f;
            }
        }
        __syncthreads();

        #pragma unroll 8
        for (int kk = 0; kk < 64; ++kk) {
            float4 a  = *(const float4*)&kl[kk * 64 + ((ty ^ (kk >> 2)) << 2)];
            float4 vv = *(const float4*)&vl[kk * 64 + ((tx ^ (kk >> 2)) << 2)];
            float av[4] = {a.x, a.y, a.z, a.w};
            float vw[4] = {vv.x, vv.y, vv.z, vv.w};
            #pragma unroll
            for (int i = 0; i < 4; ++i)
                #pragma unroll
                for (int jj = 0; jj < 4; ++jj)
                    zacc[i][jj] = fmaf(av[i], vw[jj], zacc[i][jj]);
        }
    }

    // z has row stride 1024 (separate buffer)
    const size_t zoff = ((size_t)(b * TSEQ) + (size_t)qt * 64) * 1024 + hb;
    float* zg = z + zoff;
    #pragma unroll
    for (int i = 0; i < 4; ++i) {
        float4 o = make_float4(zacc[i][0], zacc[i][1], zacc[i][2], zacc[i][3]);
        *(float4*)&zg[(size_t)(4*ty + i) * 1024 + tx * 4] = o;
    }
}

// ---------------------------------------------------------------------------
extern "C" void kernel_launch(void* const* d_in, const int* in_sizes, int n_in,
                              void* d_out, int out_size, void* d_ws, size_t ws_size,
                              hipStream_t stream)
{
    const float* x     = (const float*)d_in[0];
    const float* Wq    = (const float*)d_in[1];
    const float* Wk    = (const float*)d_in[2];
    const float* Wq2   = (const float*)d_in[3];
    const float* Wk2   = (const float*)d_in[4];
    const float* Wv    = (const float*)d_in[5];
    const float* Wproj = (const float*)d_in[6];

    // workspace layout (bytes):
    //   qkv  fp32 [4096][5120]              @ 0          (83,886,080)
    //   Xp   bf16 [4096][2048] (also Zp)    @ 83886080   (16,777,216)
    //   Wp   bf16 [6144][2048]              @ 100663296  (25,165,824)
    //     rows 0..1023   = Wproj
    //     rows 1024..6143= Wq,Wk,Wq2,Wk2,Wv (freed after qkv GEMM)
    //   zb   fp32 [4096][1024] overlays Wp rows 1024..  @ 104857600 (16,777,216)
    float*          qkv = (float*)d_ws;
    unsigned short* Xp  = (unsigned short*)((char*)d_ws + 83886080);
    unsigned short* Wp  = (unsigned short*)((char*)d_ws + 100663296);
    float*          zb  = (float*)((char*)d_ws + 104857600);

    // 1) split x -> Xp
    pack_split_kernel<<<4096, 256, 0, stream>>>(x, Xp);
    // 2) split 6 weights -> Wp (Wproj first, then the 5 projection weights)
    pack_split_w6_kernel<<<6144, 256, 0, stream>>>(Wproj, Wq, Wk, Wq2, Wk2, Wv, Wp);
    // 3) fused QKV GEMM: [4096][5120] = Xp @ (W5)^T
    gemm_split_bf16<<<dim3(32, 40), 256, 0, stream>>>(Xp, Wp + (size_t)1024 * 2048, qkv, 5120);
    // 4) RoPE in-place on q,k,q2,k2
    rope4_kernel<<<8192, 256, 0, stream>>>(qkv);
    // 5) attention (fp32)
    attn_kernel<<<dim3(TSEQ / 64, NHEAD, NBATCH), 256, 0, stream>>>(
        qkv, qkv + 1024, qkv + 2048, qkv + 3072, qkv + 4096, zb, 5120);
    // 6) split z -> Xp (reuse)
    pack_split_kernel<<<4096, 256, 0, stream>>>(zb, Xp);
    // 7) output projection: d_out = Zp @ Wproj^T
    gemm_split_bf16<<<dim3(32, 8), 256, 0, stream>>>(Xp, Wp, (float*)d_out, 1024);
}

// Round 3
// 486.087 us; speedup vs baseline: 3.3966x; 2.4614x over previous
//
#include <hip/hip_runtime.h>
#include <hip/hip_bf16.h>

#define TSEQ 2048
#define NHEAD 16
#define DM 1024
#define NBATCH 2
#define MTOK (NBATCH * TSEQ)   // 4096

typedef __attribute__((ext_vector_type(8))) short short8;
typedef __attribute__((ext_vector_type(4))) float floatx4;
typedef __attribute__((address_space(1))) const void gvoid;
typedef __attribute__((address_space(3))) void lvoid;

// ---------------------------------------------------------------------------
// bf16 helpers
// ---------------------------------------------------------------------------
static __device__ __forceinline__ unsigned short f2bf(float f) {
    unsigned int u = __float_as_uint(f);
    return (unsigned short)((u + 0x7fffu + ((u >> 16) & 1u)) >> 16);
}
static __device__ __forceinline__ float bf2f(unsigned short h) {
    return __uint_as_float(((unsigned int)h) << 16);
}
// 4 floats -> 4 bf16 (RN), written as one 8-byte store
static __device__ __forceinline__ void cvt4(float4 f, unsigned short* dst) {
    __hip_bfloat162 a = __float22bfloat162_rn(make_float2(f.x, f.y));
    __hip_bfloat162 b = __float22bfloat162_rn(make_float2(f.z, f.w));
    union { __hip_bfloat162 h2[2]; ushort4 u; } uu;
    uu.h2[0] = a; uu.h2[1] = b;
    *(ushort4*)dst = uu.u;
}

// ---------------------------------------------------------------------------
// Split fp32 -> packed bf16 [hi(1024) | lo(1024)] per row. 4 elems/thread.
// ---------------------------------------------------------------------------
__global__ __launch_bounds__(256)
void pack_split_kernel(const float* __restrict__ src, unsigned short* __restrict__ dst)
{
    int gid = blockIdx.x * 256 + threadIdx.x;
    int e   = gid * 4;
    int row = e >> 10;
    int col = e & 1023;
    float4 f = *(const float4*)(src + (size_t)row * 1024 + col);
    ushort4 hi, lo;
    hi.x = f2bf(f.x); lo.x = f2bf(f.x - bf2f(hi.x));
    hi.y = f2bf(f.y); lo.y = f2bf(f.y - bf2f(hi.y));
    hi.z = f2bf(f.z); lo.z = f2bf(f.z - bf2f(hi.z));
    hi.w = f2bf(f.w); lo.w = f2bf(f.w - bf2f(hi.w));
    *(ushort4*)(dst + (size_t)row * 2048 + col)        = hi;
    *(ushort4*)(dst + (size_t)row * 2048 + 1024 + col) = lo;
}

__global__ __launch_bounds__(256)
void pack_split_w6_kernel(const float* __restrict__ w0, const float* __restrict__ w1,
                          const float* __restrict__ w2, const float* __restrict__ w3,
                          const float* __restrict__ w4, const float* __restrict__ w5,
                          unsigned short* __restrict__ dst)
{
    int wi  = blockIdx.x >> 10;
    const float* srcs[6] = {w0, w1, w2, w3, w4, w5};
    const float* src = srcs[wi];
    int gid = (blockIdx.x & 1023) * 256 + threadIdx.x;
    int e   = gid * 4;
    int row = e >> 10;
    int col = e & 1023;
    float4 f = *(const float4*)(src + (size_t)row * 1024 + col);
    ushort4 hi, lo;
    hi.x = f2bf(f.x); lo.x = f2bf(f.x - bf2f(hi.x));
    hi.y = f2bf(f.y); lo.y = f2bf(f.y - bf2f(hi.y));
    hi.z = f2bf(f.z); lo.z = f2bf(f.z - bf2f(hi.z));
    hi.w = f2bf(f.w); lo.w = f2bf(f.w - bf2f(hi.w));
    unsigned short* d = dst + (size_t)(wi * 1024 + row) * 2048;
    *(ushort4*)(d + col)        = hi;
    *(ushort4*)(d + 1024 + col) = lo;
}

// ---------------------------------------------------------------------------
// Split-bf16 GEMM (unchanged from round 2): C[M][ldc] = A*B^T, virtual K=3072
// ---------------------------------------------------------------------------
__global__ __launch_bounds__(256)
void gemm_split_bf16(const unsigned short* __restrict__ Ap,
                     const unsigned short* __restrict__ Bp,
                     float* __restrict__ C, int ldc)
{
    __shared__ __align__(16) unsigned short As[128 * 32];
    __shared__ __align__(16) unsigned short Bs[128 * 32];

    const int t    = threadIdx.x;
    const int lane = t & 63;
    const int w    = t >> 6;
    const int row0 = blockIdx.x * 128;
    const int col0 = blockIdx.y * 128;
    const int m0   = (w >> 1) * 64;
    const int n0   = (w & 1) * 64;

    floatx4 acc[4][4];
    #pragma unroll
    for (int i = 0; i < 4; ++i)
        #pragma unroll
        for (int j = 0; j < 4; ++j)
            acc[i][j] = (floatx4)(0.0f);

    const int sr = t >> 2;
    const int sk = (t & 3) * 8;
    char* ldsA = (char*)As + (size_t)t * 16;
    char* ldsB = (char*)Bs + (size_t)t * 16;
    const size_t arow = (size_t)(row0 + sr) * 2048 + sk;
    const size_t brow = (size_t)(col0 + sr) * 2048 + sk;

    #define ISSUE(k0)                                                                     \
    {                                                                                     \
        int acol = ((k0) < 1024) ? (k0) : (k0) - 1024;                                    \
        int bcol = ((k0) < 2048) ? (k0) : (k0) - 2048;                                    \
        const unsigned short* ga = Ap + arow + acol;                                      \
        const unsigned short* gb = Bp + brow + bcol;                                      \
        __builtin_amdgcn_global_load_lds((gvoid*)ga,              (lvoid*)ldsA,        16, 0, 0); \
        __builtin_amdgcn_global_load_lds((gvoid*)(ga + 64*2048),  (lvoid*)(ldsA+4096), 16, 0, 0); \
        __builtin_amdgcn_global_load_lds((gvoid*)gb,              (lvoid*)ldsB,        16, 0, 0); \
        __builtin_amdgcn_global_load_lds((gvoid*)(gb + 64*2048),  (lvoid*)(ldsB+4096), 16, 0, 0); \
    }

    ISSUE(0);
    for (int ks = 0; ks < 96; ++ks) {
        __syncthreads();
        short8 af[4], bfr[4];
        #pragma unroll
        for (int i = 0; i < 4; ++i) {
            af[i]  = *(const short8*)&As[(m0 + i * 16 + (lane & 15)) * 32 + (lane >> 4) * 8];
            bfr[i] = *(const short8*)&Bs[(n0 + i * 16 + (lane & 15)) * 32 + (lane >> 4) * 8];
        }
        #pragma unroll
        for (int i = 0; i < 4; ++i)
            #pragma unroll
            for (int j = 0; j < 4; ++j)
                acc[i][j] = __builtin_amdgcn_mfma_f32_16x16x32_bf16(af[i], bfr[j], acc[i][j], 0, 0, 0);
        __syncthreads();
        if (ks + 1 < 96) {
            int k0 = (ks + 1) * 32;
            ISSUE(k0);
        }
    }
    #undef ISSUE

    const int cr = (lane >> 4) * 4;
    const int cc = lane & 15;
    #pragma unroll
    for (int i = 0; i < 4; ++i)
        #pragma unroll
        for (int j = 0; j < 4; ++j) {
            int r = row0 + m0 + i * 16 + cr;
            int c = col0 + n0 + j * 16 + cc;
            #pragma unroll
            for (int rr = 0; rr < 4; ++rr)
                C[(size_t)(r + rr) * ldc + c] = acc[i][j][rr];
        }
}

// ---------------------------------------------------------------------------
// RoPE in-place on q,k,q2,k2 inside qkv[4096][5120] (cols 0/1024/2048/3072)
// ---------------------------------------------------------------------------
__global__ __launch_bounds__(256)
void rope4_kernel(float* __restrict__ qkv)
{
    int idx  = blockIdx.x * 256 + threadIdx.x;
    int j    = idx & 31;
    int row  = idx >> 5;
    int tpos = (row >> 4) & (TSEQ - 1);
    int base = (row >> 4) * 5120 + (row & 15) * 64 + j;

    float inv = powf(10000.0f, -(2.0f * (float)j) / 64.0f);
    float f = (float)tpos * inv;
    float c = cosf(f);
    float s = sinf(f);

    #pragma unroll
    for (int p = 0; p < 4; ++p) {
        float* ptr = qkv + p * 1024;
        float x1 = ptr[base];
        float x2 = ptr[base + 32];
        ptr[base]      = x1 * c + x2 * s;
        ptr[base + 32] = x2 * c - x1 * s;
    }
}

// ---------------------------------------------------------------------------
// v transpose: qkv fp32 v-cols -> vt bf16 [(b*16+h)][64][2048]
// One block per (tseg of 128, h, b). LDS tile [128][68] with tok>>3 rotation.
// ---------------------------------------------------------------------------
__global__ __launch_bounds__(256)
void vtrans_kernel(const float* __restrict__ qkv, unsigned short* __restrict__ vt)
{
    __shared__ __align__(16) unsigned short tile[128 * 68];
    const int ts = blockIdx.x, h = blockIdx.y, b = blockIdx.z;
    const int t  = threadIdx.x;
    const int tok0 = t >> 4;
    const int ds4  = (t & 15) * 4;

    const float* src = qkv + ((size_t)(b * TSEQ + ts * 128 + tok0)) * 5120 + 4096 + h * 64 + ds4;
    #pragma unroll
    for (int c = 0; c < 8; ++c) {
        int tok = tok0 + 16 * c;
        float4 f = *(const float4*)(src + (size_t)(16 * c) * 5120);
        int dsw = (ds4 + 8 * ((tok >> 3) & 7)) & 63;
        cvt4(f, &tile[tok * 68 + dsw]);
    }
    __syncthreads();

    const int dv   = t >> 4;          // + 16*c2
    const int s    = t & 15;
    const int tokp = s * 8;
    #pragma unroll
    for (int c2 = 0; c2 < 4; ++c2) {
        int d = dv + 16 * c2;
        int dsw = (d + 8 * (s & 7)) & 63;
        short8 o;
        #pragma unroll
        for (int e = 0; e < 8; ++e)
            o[e] = (short)tile[(tokp + e) * 68 + dsw];
        *(short8*)(vt + ((size_t)(b * 16 + h) * 64 + d) * 2048 + ts * 128 + tokp) = o;
    }
}

// ---------------------------------------------------------------------------
// MFMA bilinear causal attention.
// Block = (b, h, q-tile 128), 4 waves. k-tiles of 128.
// S1=(q/64)kT, S2=(q2/64)k2T via 16x16x32 bf16 MFMA (fp32 acc);
// P = mask(S1*S2) -> bf16 LDS; z += P*v. z written as split-bf16 [hi|lo] to Xp.
// ---------------------------------------------------------------------------
#define LQ 72    // q/k LDS row stride (ushorts): 144 B, 16B-aligned, even banks
#define LV 136   // vT row stride
#define LP 132   // P row stride: conflict-free stores, 8B-aligned b64 reads

__global__ __launch_bounds__(256, 1)
void attn_mfma(const float* __restrict__ qkv, const unsigned short* __restrict__ vt,
               unsigned short* __restrict__ zout)
{
    __shared__ __align__(16) unsigned short qs [128 * LQ];
    __shared__ __align__(16) unsigned short q2s[128 * LQ];
    __shared__ __align__(16) unsigned short ks [128 * LQ];
    __shared__ __align__(16) unsigned short k2s[128 * LQ];
    __shared__ __align__(16) unsigned short vts[64 * LV];
    __shared__ __align__(16) unsigned short ps [128 * LP];

    const int qt = 15 - blockIdx.x;   // heavy blocks first
    const int h  = blockIdx.y;
    const int b  = blockIdx.z;
    const int t  = threadIdx.x;
    const int lane = t & 63;
    const int w    = t >> 6;
    const int s    = lane & 15;
    const int g    = lane >> 4;

    const int tok0 = t >> 4;          // staging row helper (0..15)
    const int ds4  = (t & 15) * 4;

    // ---- stage q, q2 (scaled 1/64) ----
    {
        const float* qb = qkv + ((size_t)(b * TSEQ + qt * 128 + tok0)) * 5120 + h * 64 + ds4;
        #pragma unroll
        for (int c = 0; c < 8; ++c) {
            int tok = tok0 + 16 * c;
            const float* p = qb + (size_t)(16 * c) * 5120;
            float4 fq  = *(const float4*)(p);
            float4 fq2 = *(const float4*)(p + 2048);
            const float sc = 1.0f / 64.0f;
            fq.x *= sc; fq.y *= sc; fq.z *= sc; fq.w *= sc;
            fq2.x *= sc; fq2.y *= sc; fq2.z *= sc; fq2.w *= sc;
            cvt4(fq,  &qs [tok * LQ + ds4]);
            cvt4(fq2, &q2s[tok * LQ + ds4]);
        }
    }

    floatx4 zac[2][4];
    #pragma unroll
    for (int i = 0; i < 2; ++i)
        #pragma unroll
        for (int j = 0; j < 4; ++j)
            zac[i][j] = (floatx4)(0.0f);

    const int m0 = (w >> 1) * 64;
    const int n0 = (w & 1) * 64;

    for (int tk = 0; tk <= qt; ++tk) {
        // ---- prefetch k,k2 (fp32) and vT (bf16) into regs ----
        float4 kf[8], k2f[8];
        const float* kb = qkv + ((size_t)(b * TSEQ + tk * 128 + tok0)) * 5120 + 1024 + h * 64 + ds4;
        #pragma unroll
        for (int c = 0; c < 8; ++c) {
            const float* p = kb + (size_t)(16 * c) * 5120;
            kf[c]  = *(const float4*)p;
            k2f[c] = *(const float4*)(p + 2048);
        }
        short8 vf[4];
        const unsigned short* vb = vt + ((size_t)(b * 16 + h) * 64 + tok0) * 2048 + tk * 128 + s * 8;
        #pragma unroll
        for (int c2 = 0; c2 < 4; ++c2)
            vf[c2] = *(const short8*)(vb + (size_t)(16 * c2) * 2048);

        __syncthreads();   // barrier0: prev PV done reading vts/ps; prev S done reading ks

        #pragma unroll
        for (int c = 0; c < 8; ++c) {
            int tok = tok0 + 16 * c;
            cvt4(kf[c],  &ks [tok * LQ + ds4]);
            cvt4(k2f[c], &k2s[tok * LQ + ds4]);
        }
        #pragma unroll
        for (int c2 = 0; c2 < 4; ++c2)
            *(short8*)&vts[(tok0 + 16 * c2) * LV + s * 8] = vf[c2];

        __syncthreads();   // barrier1: tiles visible

        // ---- S phase ----
        floatx4 a1[4][4], a2[4][4];
        #pragma unroll
        for (int i = 0; i < 4; ++i)
            #pragma unroll
            for (int j = 0; j < 4; ++j) { a1[i][j] = (floatx4)(0.0f); a2[i][j] = (floatx4)(0.0f); }

        #pragma unroll
        for (int kstep = 0; kstep < 2; ++kstep) {
            const int dd = g * 8 + kstep * 32;
            short8 aq[4], aq2[4], bk[4], bk2[4];
            #pragma unroll
            for (int i = 0; i < 4; ++i) {
                int r = (m0 + i * 16 + s) * LQ + dd;
                aq[i]  = *(const short8*)&qs [r];
                aq2[i] = *(const short8*)&q2s[r];
            }
            #pragma unroll
            for (int j = 0; j < 4; ++j) {
                int r = (n0 + j * 16 + s) * LQ + dd;
                bk[j]  = *(const short8*)&ks [r];
                bk2[j] = *(const short8*)&k2s[r];
            }
            #pragma unroll
            for (int i = 0; i < 4; ++i)
                #pragma unroll
                for (int j = 0; j < 4; ++j) {
                    a1[i][j] = __builtin_amdgcn_mfma_f32_16x16x32_bf16(aq[i],  bk[j],  a1[i][j], 0, 0, 0);
                    a2[i][j] = __builtin_amdgcn_mfma_f32_16x16x32_bf16(aq2[i], bk2[j], a2[i][j], 0, 0, 0);
                }
        }

        // ---- P = S1*S2 (masked on diagonal), store bf16 to ps ----
        if (tk < qt) {
            #pragma unroll
            for (int i = 0; i < 4; ++i)
                #pragma unroll
                for (int j = 0; j < 4; ++j) {
                    const int rbase = m0 + i * 16 + g * 4;
                    const int col   = n0 + j * 16 + s;
                    #pragma unroll
                    for (int r = 0; r < 4; r += 2) {
                        float p0 = a1[i][j][r]     * a2[i][j][r];
                        float p1 = a1[i][j][r + 1] * a2[i][j][r + 1];
                        __hip_bfloat162 pk = __float22bfloat162_rn(make_float2(p0, p1));
                        union { __hip_bfloat162 h; unsigned int u; } uu; uu.h = pk;
                        ps[(rbase + r)     * LP + col] = (unsigned short)(uu.u & 0xffffu);
                        ps[(rbase + r + 1) * LP + col] = (unsigned short)(uu.u >> 16);
                    }
                }
        } else {
            #pragma unroll
            for (int i = 0; i < 4; ++i)
                #pragma unroll
                for (int j = 0; j < 4; ++j) {
                    const int rbase = m0 + i * 16 + g * 4;
                    const int col   = n0 + j * 16 + s;
                    #pragma unroll
                    for (int r = 0; r < 4; r += 2) {
                        float p0 = (col <= rbase + r)     ? a1[i][j][r]     * a2[i][j][r]     : 0.0f;
                        float p1 = (col <= rbase + r + 1) ? a1[i][j][r + 1] * a2[i][j][r + 1] : 0.0f;
                        __hip_bfloat162 pk = __float22bfloat162_rn(make_float2(p0, p1));
                        union { __hip_bfloat162 h; unsigned int u; } uu; uu.h = pk;
                        ps[(rbase + r)     * LP + col] = (unsigned short)(uu.u & 0xffffu);
                        ps[(rbase + r + 1) * LP + col] = (unsigned short)(uu.u >> 16);
                    }
                }
        }

        __syncthreads();   // barrier2: ps visible

        // ---- PV: z[m][d] += P[m][n] * vT[d][n] ----
        const int wm0 = w * 32;
        #pragma unroll
        for (int ns = 0; ns < 4; ++ns) {
            const int nn = g * 8 + ns * 32;
            short8 ap[2], bv[4];
            #pragma unroll
            for (int i2 = 0; i2 < 2; ++i2) {
                const int idx = (wm0 + i2 * 16 + s) * LP + nn;
                short4 lo4 = *(const short4*)&ps[idx];
                short4 hi4 = *(const short4*)&ps[idx + 4];
                short8 v8;
                v8[0] = lo4.x; v8[1] = lo4.y; v8[2] = lo4.z; v8[3] = lo4.w;
                v8[4] = hi4.x; v8[5] = hi4.y; v8[6] = hi4.z; v8[7] = hi4.w;
                ap[i2] = v8;
            }
            #pragma unroll
            for (int j = 0; j < 4; ++j)
                bv[j] = *(const short8*)&vts[(j * 16 + s) * LV + nn];
            #pragma unroll
            for (int i2 = 0; i2 < 2; ++i2)
                #pragma unroll
                for (int j = 0; j < 4; ++j)
                    zac[i2][j] = __builtin_amdgcn_mfma_f32_16x16x32_bf16(ap[i2], bv[j], zac[i2][j], 0, 0, 0);
        }
    }

    // ---- epilogue: z -> split bf16 [hi | lo] into zout[4096][2048] ----
    const size_t zrow0 = (size_t)(b * TSEQ + qt * 128);
    #pragma unroll
    for (int i2 = 0; i2 < 2; ++i2)
        #pragma unroll
        for (int j = 0; j < 4; ++j)
            #pragma unroll
            for (int r = 0; r < 4; ++r) {
                float zv = zac[i2][j][r];
                unsigned short hi = f2bf(zv);
                unsigned short lo = f2bf(zv - bf2f(hi));
                size_t row = zrow0 + w * 32 + i2 * 16 + g * 4 + r;
                int col = h * 64 + j * 16 + s;
                zout[row * 2048 + col]        = hi;
                zout[row * 2048 + 1024 + col] = lo;
            }
}

// ---------------------------------------------------------------------------
extern "C" void kernel_launch(void* const* d_in, const int* in_sizes, int n_in,
                              void* d_out, int out_size, void* d_ws, size_t ws_size,
                              hipStream_t stream)
{
    const float* x     = (const float*)d_in[0];
    const float* Wq    = (const float*)d_in[1];
    const float* Wk    = (const float*)d_in[2];
    const float* Wq2   = (const float*)d_in[3];
    const float* Wk2   = (const float*)d_in[4];
    const float* Wv    = (const float*)d_in[5];
    const float* Wproj = (const float*)d_in[6];

    // workspace layout (bytes):
    //   qkv fp32 [4096][5120]            @ 0            (83,886,080)
    //   Xp  bf16 [4096][2048] (x, then z)@ 83,886,080   (16,777,216)
    //   Wp  bf16 [6144][2048]            @ 100,663,296  (25,165,824; ends 125,829,120)
    //     rows 0..1023 = Wproj (live until last GEMM)
    //     rows 1024..  = Wq..Wv (dead after qkv GEMM)
    //   vt  bf16 [32][64][2048]          @ 104,857,600  (8,388,608; inside dead Wp rows)
    float*          qkv = (float*)d_ws;
    unsigned short* Xp  = (unsigned short*)((char*)d_ws + 83886080);
    unsigned short* Wp  = (unsigned short*)((char*)d_ws + 100663296);
    unsigned short* vt  = (unsigned short*)((char*)d_ws + 104857600);

    pack_split_kernel<<<4096, 256, 0, stream>>>(x, Xp);
    pack_split_w6_kernel<<<6144, 256, 0, stream>>>(Wproj, Wq, Wk, Wq2, Wk2, Wv, Wp);
    gemm_split_bf16<<<dim3(32, 40), 256, 0, stream>>>(Xp, Wp + (size_t)1024 * 2048, qkv, 5120);
    rope4_kernel<<<8192, 256, 0, stream>>>(qkv);
    vtrans_kernel<<<dim3(16, 16, 2), 256, 0, stream>>>(qkv, vt);
    attn_mfma<<<dim3(16, 16, 2), 256, 0, stream>>>(qkv, vt, Xp);   // z -> Xp (split bf16)
    gemm_split_bf16<<<dim3(32, 8), 256, 0, stream>>>(Xp, Wp, (float*)d_out, 1024);
}

// Round 4
// 400.123 us; speedup vs baseline: 4.1263x; 1.2148x over previous
//
#include <hip/hip_runtime.h>
#include <hip/hip_bf16.h>

#define TSEQ 2048
#define NHEAD 16
#define DM 1024
#define NBATCH 2
#define MTOK (NBATCH * TSEQ)   // 4096

typedef __attribute__((ext_vector_type(8))) short short8;
typedef __attribute__((ext_vector_type(4))) float floatx4;
typedef __attribute__((address_space(1))) const void gvoid;
typedef __attribute__((address_space(3))) void lvoid;

static __device__ __forceinline__ unsigned short f2bf(float f) {
    unsigned int u = __float_as_uint(f);
    return (unsigned short)((u + 0x7fffu + ((u >> 16) & 1u)) >> 16);
}
static __device__ __forceinline__ float bf2f(unsigned short h) {
    return __uint_as_float(((unsigned int)h) << 16);
}

// ---------------------------------------------------------------------------
// Split fp32 -> packed bf16 [hi(1024) | lo(1024)] per row.
// ---------------------------------------------------------------------------
__global__ __launch_bounds__(256)
void pack_split_kernel(const float* __restrict__ src, unsigned short* __restrict__ dst)
{
    int gid = blockIdx.x * 256 + threadIdx.x;
    int e   = gid * 4;
    int row = e >> 10;
    int col = e & 1023;
    float4 f = *(const float4*)(src + (size_t)row * 1024 + col);
    ushort4 hi, lo;
    hi.x = f2bf(f.x); lo.x = f2bf(f.x - bf2f(hi.x));
    hi.y = f2bf(f.y); lo.y = f2bf(f.y - bf2f(hi.y));
    hi.z = f2bf(f.z); lo.z = f2bf(f.z - bf2f(hi.z));
    hi.w = f2bf(f.w); lo.w = f2bf(f.w - bf2f(hi.w));
    *(ushort4*)(dst + (size_t)row * 2048 + col)        = hi;
    *(ushort4*)(dst + (size_t)row * 2048 + 1024 + col) = lo;
}

__global__ __launch_bounds__(256)
void pack_split_w6_kernel(const float* __restrict__ w0, const float* __restrict__ w1,
                          const float* __restrict__ w2, const float* __restrict__ w3,
                          const float* __restrict__ w4, const float* __restrict__ w5,
                          unsigned short* __restrict__ dst)
{
    int wi  = blockIdx.x >> 10;
    const float* srcs[6] = {w0, w1, w2, w3, w4, w5};
    const float* src = srcs[wi];
    int gid = (blockIdx.x & 1023) * 256 + threadIdx.x;
    int e   = gid * 4;
    int row = e >> 10;
    int col = e & 1023;
    float4 f = *(const float4*)(src + (size_t)row * 1024 + col);
    ushort4 hi, lo;
    hi.x = f2bf(f.x); lo.x = f2bf(f.x - bf2f(hi.x));
    hi.y = f2bf(f.y); lo.y = f2bf(f.y - bf2f(hi.y));
    hi.z = f2bf(f.z); lo.z = f2bf(f.z - bf2f(hi.z));
    hi.w = f2bf(f.w); lo.w = f2bf(f.w - bf2f(hi.w));
    unsigned short* d = dst + (size_t)(wi * 1024 + row) * 2048;
    *(ushort4*)(d + col)        = hi;
    *(ushort4*)(d + 1024 + col) = lo;
}

// ---------------------------------------------------------------------------
// Split-bf16 GEMM, two modes.
// mode 0 (proj): 3-term (virtual K=3072), fp32 output [4096][1024].
// mode 1 (qkv):  2-term (virtual K=2048: A=[hi|lo], B=[hi|hi] => x @ bf16(W)),
//                bf16 output scattered head-major: heads[p][bh][t][64].
// ---------------------------------------------------------------------------
__global__ __launch_bounds__(256)
void gemm_split_bf16(const unsigned short* __restrict__ Ap,
                     const unsigned short* __restrict__ Bp,
                     float* __restrict__ Cf, unsigned short* __restrict__ Ch,
                     int mode)
{
    __shared__ __align__(16) unsigned short As[128 * 32];
    __shared__ __align__(16) unsigned short Bs[128 * 32];

    const int t    = threadIdx.x;
    const int lane = t & 63;
    const int w    = t >> 6;
    const int row0 = blockIdx.x * 128;
    const int col0 = blockIdx.y * 128;
    const int m0   = (w >> 1) * 64;
    const int n0   = (w & 1) * 64;
    const int nk   = mode ? 64 : 96;

    floatx4 acc[4][4];
    #pragma unroll
    for (int i = 0; i < 4; ++i)
        #pragma unroll
        for (int j = 0; j < 4; ++j)
            acc[i][j] = (floatx4)(0.0f);

    const int sr = t >> 2;
    const int sk = (t & 3) * 8;
    char* ldsA = (char*)As + (size_t)t * 16;
    char* ldsB = (char*)Bs + (size_t)t * 16;
    const size_t arow = (size_t)(row0 + sr) * 2048 + sk;
    const size_t brow = (size_t)(col0 + sr) * 2048 + sk;

    #define ISSUE(k0)                                                                     \
    {                                                                                     \
        int acol = mode ? (k0) : (((k0) < 1024) ? (k0) : (k0) - 1024);                    \
        int bcol = mode ? ((k0) & 1023) : (((k0) < 2048) ? (k0) : (k0) - 2048);           \
        const unsigned short* ga = Ap + arow + acol;                                      \
        const unsigned short* gb = Bp + brow + bcol;                                      \
        __builtin_amdgcn_global_load_lds((gvoid*)ga,              (lvoid*)ldsA,        16, 0, 0); \
        __builtin_amdgcn_global_load_lds((gvoid*)(ga + 64*2048),  (lvoid*)(ldsA+4096), 16, 0, 0); \
        __builtin_amdgcn_global_load_lds((gvoid*)gb,              (lvoid*)ldsB,        16, 0, 0); \
        __builtin_amdgcn_global_load_lds((gvoid*)(gb + 64*2048),  (lvoid*)(ldsB+4096), 16, 0, 0); \
    }

    ISSUE(0);
    for (int ks = 0; ks < nk; ++ks) {
        __syncthreads();
        short8 af[4], bfr[4];
        #pragma unroll
        for (int i = 0; i < 4; ++i) {
            af[i]  = *(const short8*)&As[(m0 + i * 16 + (lane & 15)) * 32 + (lane >> 4) * 8];
            bfr[i] = *(const short8*)&Bs[(n0 + i * 16 + (lane & 15)) * 32 + (lane >> 4) * 8];
        }
        #pragma unroll
        for (int i = 0; i < 4; ++i)
            #pragma unroll
            for (int j = 0; j < 4; ++j)
                acc[i][j] = __builtin_amdgcn_mfma_f32_16x16x32_bf16(af[i], bfr[j], acc[i][j], 0, 0, 0);
        __syncthreads();
        if (ks + 1 < nk) {
            int k0 = (ks + 1) * 32;
            ISSUE(k0);
        }
    }
    #undef ISSUE

    const int cr = (lane >> 4) * 4;
    const int cc = lane & 15;
    if (mode == 0) {
        #pragma unroll
        for (int i = 0; i < 4; ++i)
            #pragma unroll
            for (int j = 0; j < 4; ++j) {
                int r = row0 + m0 + i * 16 + cr;
                int c = col0 + n0 + j * 16 + cc;
                #pragma unroll
                for (int rr = 0; rr < 4; ++rr)
                    Cf[(size_t)(r + rr) * 1024 + c] = acc[i][j][rr];
            }
    } else {
        // scatter to heads[p][bh][t][64]: p=c>>10, h=(c>>6)&15, d=c&63, b=r>>11
        #pragma unroll
        for (int i = 0; i < 4; ++i)
            #pragma unroll
            for (int j = 0; j < 4; ++j) {
                int c = col0 + n0 + j * 16 + cc;
                int p = c >> 10, h = (c >> 6) & 15, d = c & 63;
                #pragma unroll
                for (int rr = 0; rr < 4; ++rr) {
                    int r = row0 + m0 + i * 16 + cr + rr;
                    size_t dst = (((size_t)(p * 32 + ((r >> 11) << 4) + h)) * 2048
                                  + (r & 2047)) * 64 + d;
                    Ch[dst] = f2bf(acc[i][j][rr]);
                }
            }
    }
}

// ---------------------------------------------------------------------------
// RoPE in-place on head-major bf16 q,k,q2,k2; q,q2 also scaled by 1/64.
// ---------------------------------------------------------------------------
__global__ __launch_bounds__(256)
void rope_bf16_kernel(unsigned short* __restrict__ qh, unsigned short* __restrict__ q2h,
                      unsigned short* __restrict__ kh, unsigned short* __restrict__ k2h)
{
    int idx = blockIdx.x * 256 + threadIdx.x;     // 32*2048*32
    int j   = idx & 31;
    int tt  = (idx >> 5) & 2047;
    int bh  = idx >> 16;
    size_t base = ((size_t)bh * 2048 + tt) * 64 + j;

    float inv = powf(10000.0f, -(float)j / 32.0f);
    float f = (float)tt * inv;
    float c = cosf(f), s = sinf(f);

    {   // q (scale 1/64)
        float x1 = bf2f(qh[base]), x2 = bf2f(qh[base + 32]);
        qh[base]      = f2bf((x1 * c + x2 * s) * 0.015625f);
        qh[base + 32] = f2bf((x2 * c - x1 * s) * 0.015625f);
    }
    {   // q2 (scale 1/64)
        float x1 = bf2f(q2h[base]), x2 = bf2f(q2h[base + 32]);
        q2h[base]      = f2bf((x1 * c + x2 * s) * 0.015625f);
        q2h[base + 32] = f2bf((x2 * c - x1 * s) * 0.015625f);
    }
    {   // k
        float x1 = bf2f(kh[base]), x2 = bf2f(kh[base + 32]);
        kh[base]      = f2bf(x1 * c + x2 * s);
        kh[base + 32] = f2bf(x2 * c - x1 * s);
    }
    {   // k2
        float x1 = bf2f(k2h[base]), x2 = bf2f(k2h[base + 32]);
        k2h[base]      = f2bf(x1 * c + x2 * s);
        k2h[base + 32] = f2bf(x2 * c - x1 * s);
    }
}

// ---------------------------------------------------------------------------
// v transpose: vh[bh][t][64] bf16 -> vt[bh][64][2048] bf16.
// LDS tile [128][72] with (tok>>3) rotation on 8-col groups.
// ---------------------------------------------------------------------------
__global__ __launch_bounds__(256)
void vtrans_kernel(const unsigned short* __restrict__ vh, unsigned short* __restrict__ vt)
{
    __shared__ __align__(16) unsigned short tile[128 * 72];
    const int ts = blockIdx.x;   // 0..15
    const int bh = blockIdx.y;   // 0..31
    const int t  = threadIdx.x;

    const unsigned short* src = vh + ((size_t)bh * 2048 + ts * 128) * 64;
    const int tok = t >> 1;
    #pragma unroll
    for (int c = 0; c < 4; ++c) {
        int cg = (t & 1) * 4 + c;
        short8 vls = *(const short8*)(src + (size_t)tok * 64 + cg * 8);
        int cgm = (cg + (tok >> 3)) & 7;
        *(short8*)&tile[tok * 72 + cgm * 8] = vls;
    }
    __syncthreads();

    const int s    = t & 15;
    const int tokp = s * 8;
    #pragma unroll
    for (int c2 = 0; c2 < 4; ++c2) {
        int d = (t >> 4) + 16 * c2;
        short8 o;
        #pragma unroll
        for (int e = 0; e < 8; ++e) {
            int cgm = ((d >> 3) + s) & 7;
            o[e] = (short)tile[(tokp + e) * 72 + cgm * 8 + (d & 7)];
        }
        *(short8*)(vt + ((size_t)bh * 64 + d) * 2048 + ts * 128 + tokp) = o;
    }
}

// ---------------------------------------------------------------------------
// MFMA bilinear causal attention, all-bf16 staging.
// Block=(qt 128-row tile, bh), 4 waves. Rotated LDS layouts (<=2-way, free).
// q,q2 pre-scaled 1/64 => P = S1*S2 directly. z -> split-bf16 [hi|lo] in zout.
// ---------------------------------------------------------------------------
#define LP 132

__global__ __launch_bounds__(256, 1)
void attn_mfma(const unsigned short* __restrict__ qh, const unsigned short* __restrict__ q2h,
               const unsigned short* __restrict__ kh, const unsigned short* __restrict__ k2h,
               const unsigned short* __restrict__ vt, unsigned short* __restrict__ zout)
{
    __shared__ __align__(16) unsigned short qs [128 * 64];
    __shared__ __align__(16) unsigned short q2s[128 * 64];
    __shared__ __align__(16) unsigned short ks [128 * 64];
    __shared__ __align__(16) unsigned short k2s[128 * 64];
    __shared__ __align__(16) unsigned short vts[64 * 128];
    __shared__ __align__(16) unsigned short ps [128 * LP];

    const int qt = 15 - blockIdx.x;   // heavy blocks first
    const int bh = blockIdx.y;
    const int t  = threadIdx.x;
    const int lane = t & 63;
    const int w    = t >> 6;
    const int s    = lane & 15;
    const int g    = lane >> 4;
    const int m0   = (w >> 1) * 64;
    const int n0   = (w & 1) * 64;

    // ---- stage q, q2 (once) ----
    {
        const unsigned short* qb  = qh  + ((size_t)bh * 2048 + qt * 128) * 64;
        const unsigned short* q2b = q2h + ((size_t)bh * 2048 + qt * 128) * 64;
        const int row = t >> 1;
        #pragma unroll
        for (int c = 0; c < 4; ++c) {
            int cg  = (t & 1) * 4 + c;
            short8 a  = *(const short8*)(qb  + (size_t)row * 64 + cg * 8);
            short8 a2 = *(const short8*)(q2b + (size_t)row * 64 + cg * 8);
            int cgm = (cg + row) & 7;
            *(short8*)&qs [row * 64 + cgm * 8] = a;
            *(short8*)&q2s[row * 64 + cgm * 8] = a2;
        }
    }

    floatx4 zac[2][4];
    #pragma unroll
    for (int i = 0; i < 2; ++i)
        #pragma unroll
        for (int j = 0; j < 4; ++j)
            zac[i][j] = (floatx4)(0.0f);

    for (int tk = 0; tk <= qt; ++tk) {
        // ---- register prefetch (bf16) ----
        short8 kf[4], k2f[4], vf[4];
        {
            const unsigned short* kb  = kh  + ((size_t)bh * 2048 + tk * 128) * 64;
            const unsigned short* k2b = k2h + ((size_t)bh * 2048 + tk * 128) * 64;
            const unsigned short* vb  = vt  + (size_t)bh * 131072 + tk * 128;
            const int krow = t >> 1;
            const int vd   = t >> 2;
            #pragma unroll
            for (int c = 0; c < 4; ++c) {
                int cg = (t & 1) * 4 + c;
                kf[c]  = *(const short8*)(kb  + (size_t)krow * 64 + cg * 8);
                k2f[c] = *(const short8*)(k2b + (size_t)krow * 64 + cg * 8);
                int cg16 = 4 * (t & 3) + c;
                vf[c]  = *(const short8*)(vb + (size_t)vd * 2048 + cg16 * 8);
            }
        }
        __syncthreads();   // barrier0: prev S done with ks/k2s, prev PV done with vts/ps
        {
            const int krow = t >> 1;
            const int vd   = t >> 2;
            #pragma unroll
            for (int c = 0; c < 4; ++c) {
                int cg  = (t & 1) * 4 + c;
                int cgm = (cg + krow) & 7;
                *(short8*)&ks [krow * 64 + cgm * 8] = kf[c];
                *(short8*)&k2s[krow * 64 + cgm * 8] = k2f[c];
                int cg16 = 4 * (t & 3) + c;
                int cgm16 = (cg16 + vd) & 15;
                *(short8*)&vts[vd * 128 + cgm16 * 8] = vf[c];
            }
        }
        __syncthreads();   // barrier1: tiles visible

        // ---- S phase ----
        floatx4 a1[4][4], a2[4][4];
        #pragma unroll
        for (int i = 0; i < 4; ++i)
            #pragma unroll
            for (int j = 0; j < 4; ++j) { a1[i][j] = (floatx4)(0.0f); a2[i][j] = (floatx4)(0.0f); }

        #pragma unroll
        for (int kstep = 0; kstep < 2; ++kstep) {
            const int gl = kstep * 4 + g;
            short8 aq[4], aq2[4], bk[4], bk2[4];
            #pragma unroll
            for (int i = 0; i < 4; ++i) {
                int m = m0 + i * 16 + s;
                int a = m * 64 + ((gl + m) & 7) * 8;
                aq[i]  = *(const short8*)&qs [a];
                aq2[i] = *(const short8*)&q2s[a];
            }
            #pragma unroll
            for (int j = 0; j < 4; ++j) {
                int n = n0 + j * 16 + s;
                int a = n * 64 + ((gl + n) & 7) * 8;
                bk[j]  = *(const short8*)&ks [a];
                bk2[j] = *(const short8*)&k2s[a];
            }
            #pragma unroll
            for (int i = 0; i < 4; ++i)
                #pragma unroll
                for (int j = 0; j < 4; ++j) {
                    a1[i][j] = __builtin_amdgcn_mfma_f32_16x16x32_bf16(aq[i],  bk[j],  a1[i][j], 0, 0, 0);
                    a2[i][j] = __builtin_amdgcn_mfma_f32_16x16x32_bf16(aq2[i], bk2[j], a2[i][j], 0, 0, 0);
                }
        }

        // ---- P = S1*S2 (diagonal tile masked) -> bf16 ps ----
        if (tk < qt) {
            #pragma unroll
            for (int i = 0; i < 4; ++i)
                #pragma unroll
                for (int j = 0; j < 4; ++j) {
                    const int rbase = m0 + i * 16 + g * 4;
                    const int col   = n0 + j * 16 + s;
                    #pragma unroll
                    for (int r = 0; r < 4; ++r)
                        ps[(rbase + r) * LP + col] = f2bf(a1[i][j][r] * a2[i][j][r]);
                }
        } else {
            #pragma unroll
            for (int i = 0; i < 4; ++i)
                #pragma unroll
                for (int j = 0; j < 4; ++j) {
                    const int rbase = m0 + i * 16 + g * 4;
                    const int col   = n0 + j * 16 + s;
                    #pragma unroll
                    for (int r = 0; r < 4; ++r) {
                        float p = (col <= rbase + r) ? a1[i][j][r] * a2[i][j][r] : 0.0f;
                        ps[(rbase + r) * LP + col] = f2bf(p);
                    }
                }
        }

        __syncthreads();   // barrier2: ps visible

        // ---- PV: z[m][d] += P[m][n] * vT[d][n] ----
        const int wm0 = w * 32;
        #pragma unroll
        for (int ns = 0; ns < 4; ++ns) {
            const int nn = g * 8 + ns * 32;
            const int nl = g + ns * 4;
            short8 ap[2], bv[4];
            #pragma unroll
            for (int i2 = 0; i2 < 2; ++i2) {
                const int idx = (wm0 + i2 * 16 + s) * LP + nn;
                short4 lo4 = *(const short4*)&ps[idx];
                short4 hi4 = *(const short4*)&ps[idx + 4];
                short8 v8;
                v8[0] = lo4.x; v8[1] = lo4.y; v8[2] = lo4.z; v8[3] = lo4.w;
                v8[4] = hi4.x; v8[5] = hi4.y; v8[6] = hi4.z; v8[7] = hi4.w;
                ap[i2] = v8;
            }
            #pragma unroll
            for (int j = 0; j < 4; ++j) {
                int dd = j * 16 + s;
                bv[j] = *(const short8*)&vts[dd * 128 + ((nl + dd) & 15) * 8];
            }
            #pragma unroll
            for (int i2 = 0; i2 < 2; ++i2)
                #pragma unroll
                for (int j = 0; j < 4; ++j)
                    zac[i2][j] = __builtin_amdgcn_mfma_f32_16x16x32_bf16(ap[i2], bv[j], zac[i2][j], 0, 0, 0);
        }
    }

    // ---- epilogue: z -> split bf16 [hi | lo] into zout[4096][2048] ----
    const int b = bh >> 4, h = bh & 15;
    const size_t zrow0 = (size_t)(b * TSEQ + qt * 128);
    #pragma unroll
    for (int i2 = 0; i2 < 2; ++i2)
        #pragma unroll
        for (int j = 0; j < 4; ++j)
            #pragma unroll
            for (int r = 0; r < 4; ++r) {
                float zv = zac[i2][j][r];
                unsigned short hi = f2bf(zv);
                unsigned short lo = f2bf(zv - bf2f(hi));
                size_t row = zrow0 + w * 32 + i2 * 16 + g * 4 + r;
                int col = h * 64 + j * 16 + s;
                zout[row * 2048 + col]        = hi;
                zout[row * 2048 + 1024 + col] = lo;
            }
}

// ---------------------------------------------------------------------------
extern "C" void kernel_launch(void* const* d_in, const int* in_sizes, int n_in,
                              void* d_out, int out_size, void* d_ws, size_t ws_size,
                              hipStream_t stream)
{
    const float* x     = (const float*)d_in[0];
    const float* Wq    = (const float*)d_in[1];
    const float* Wk    = (const float*)d_in[2];
    const float* Wq2   = (const float*)d_in[3];
    const float* Wk2   = (const float*)d_in[4];
    const float* Wv    = (const float*)d_in[5];
    const float* Wproj = (const float*)d_in[6];

    // workspace (bytes):
    //   Xp    bf16 [4096][2048] (x-split, later z-split) @ 0          (16,777,216)
    //   Wp    bf16 [6144][2048]                          @ 16,777,216 (25,165,824)
    //     rows 0..1023 = Wproj ; rows 1024.. = Wq,Wk,Wq2,Wk2,Wv
    //   heads bf16 [5][32][2048][64] (q,k,q2,k2,v)       @ 41,943,040 (41,943,040)
    //   vt    bf16 [32][64][2048]                        @ 83,886,080 ( 8,388,608)
    //   total 92,274,688
    unsigned short* Xp    = (unsigned short*)d_ws;
    unsigned short* Wp    = (unsigned short*)((char*)d_ws + 16777216);
    unsigned short* heads = (unsigned short*)((char*)d_ws + 41943040);
    unsigned short* vt    = (unsigned short*)((char*)d_ws + 83886080);

    const size_t HS = (size_t)32 * 2048 * 64;   // 4,194,304 ushorts per tensor
    unsigned short* qh  = heads;
    unsigned short* kh  = heads + 1 * HS;
    unsigned short* q2h = heads + 2 * HS;
    unsigned short* k2h = heads + 3 * HS;
    unsigned short* vh  = heads + 4 * HS;

    pack_split_kernel<<<4096, 256, 0, stream>>>(x, Xp);
    pack_split_w6_kernel<<<6144, 256, 0, stream>>>(Wproj, Wq, Wk, Wq2, Wk2, Wv, Wp);
    // qkv GEMM (2-term), bf16 head-major scatter into heads[p][bh][t][64]
    gemm_split_bf16<<<dim3(32, 40), 256, 0, stream>>>(Xp, Wp + (size_t)1024 * 2048,
                                                      nullptr, heads, 1);
    rope_bf16_kernel<<<8192, 256, 0, stream>>>(qh, q2h, kh, k2h);
    vtrans_kernel<<<dim3(16, 32), 256, 0, stream>>>(vh, vt);
    attn_mfma<<<dim3(16, 32), 256, 0, stream>>>(qh, q2h, kh, k2h, vt, Xp);
    // output projection (3-term, fp32 out)
    gemm_split_bf16<<<dim3(32, 8), 256, 0, stream>>>(Xp, Wp, (float*)d_out, nullptr, 0);
}

// Round 5
// 322.270 us; speedup vs baseline: 5.1231x; 1.2416x over previous
//
#include <hip/hip_runtime.h>
#include <hip/hip_bf16.h>

#define TSEQ 2048
#define NHEAD 16
#define DM 1024
#define NBATCH 2
#define MTOK (NBATCH * TSEQ)   // 4096

typedef __attribute__((ext_vector_type(8))) short short8;
typedef __attribute__((ext_vector_type(4))) float floatx4;
typedef __attribute__((address_space(1))) const void gvoid;
typedef __attribute__((address_space(3))) void lvoid;

static __device__ __forceinline__ unsigned short f2bf(float f) {
    unsigned int u = __float_as_uint(f);
    return (unsigned short)((u + 0x7fffu + ((u >> 16) & 1u)) >> 16);
}
static __device__ __forceinline__ float bf2f(unsigned short h) {
    return __uint_as_float(((unsigned int)h) << 16);
}

// ---------------------------------------------------------------------------
// Split fp32 -> packed bf16 [hi(1024) | lo(1024)] per row.
// ---------------------------------------------------------------------------
__global__ __launch_bounds__(256)
void pack_split_kernel(const float* __restrict__ src, unsigned short* __restrict__ dst)
{
    int gid = blockIdx.x * 256 + threadIdx.x;
    int e   = gid * 4;
    int row = e >> 10;
    int col = e & 1023;
    float4 f = *(const float4*)(src + (size_t)row * 1024 + col);
    ushort4 hi, lo;
    hi.x = f2bf(f.x); lo.x = f2bf(f.x - bf2f(hi.x));
    hi.y = f2bf(f.y); lo.y = f2bf(f.y - bf2f(hi.y));
    hi.z = f2bf(f.z); lo.z = f2bf(f.z - bf2f(hi.z));
    hi.w = f2bf(f.w); lo.w = f2bf(f.w - bf2f(hi.w));
    *(ushort4*)(dst + (size_t)row * 2048 + col)        = hi;
    *(ushort4*)(dst + (size_t)row * 2048 + 1024 + col) = lo;
}

__global__ __launch_bounds__(256)
void pack_split_w6_kernel(const float* __restrict__ w0, const float* __restrict__ w1,
                          const float* __restrict__ w2, const float* __restrict__ w3,
                          const float* __restrict__ w4, const float* __restrict__ w5,
                          unsigned short* __restrict__ dst)
{
    int wi  = blockIdx.x >> 10;
    const float* srcs[6] = {w0, w1, w2, w3, w4, w5};
    const float* src = srcs[wi];
    int gid = (blockIdx.x & 1023) * 256 + threadIdx.x;
    int e   = gid * 4;
    int row = e >> 10;
    int col = e & 1023;
    float4 f = *(const float4*)(src + (size_t)row * 1024 + col);
    ushort4 hi, lo;
    hi.x = f2bf(f.x); lo.x = f2bf(f.x - bf2f(hi.x));
    hi.y = f2bf(f.y); lo.y = f2bf(f.y - bf2f(hi.y));
    hi.z = f2bf(f.z); lo.z = f2bf(f.z - bf2f(hi.z));
    hi.w = f2bf(f.w); lo.w = f2bf(f.w - bf2f(hi.w));
    unsigned short* d = dst + (size_t)(wi * 1024 + row) * 2048;
    *(ushort4*)(d + col)        = hi;
    *(ushort4*)(d + 1024 + col) = lo;
}

// ---------------------------------------------------------------------------
// Split-bf16 GEMM, shared-B K-loop (real K=1024, BK=32, 32 iters).
// mode 1 (qkv):  C = (hiA+loA)*hiB^T ; epilogue fuses RoPE + q-scale and
//                scatters bf16 head-major to heads[p][bh][t][64] (p=q,k,q2,k2)
//                and v transposed to Vt[bh][64][2048].
// mode 0 (proj): C = (hiA+loA)*hiB^T + hiA*loB^T, fp32 out [4096][1024].
// LDS anti-conflict: source-chunk XOR (LDS[row][c] = G[row][c ^ ((row>>1)&3)])
// keeps global_load_lds dst linear while spreading read start-banks.
// ---------------------------------------------------------------------------
__global__ __launch_bounds__(256)
void gemm_split_bf16(const unsigned short* __restrict__ Ap,
                     const unsigned short* __restrict__ Bp,
                     float* __restrict__ Cf, unsigned short* __restrict__ Ch,
                     unsigned short* __restrict__ Vt, int mode)
{
    __shared__ __align__(16) unsigned short Ah[128 * 32];
    __shared__ __align__(16) unsigned short Al[128 * 32];
    __shared__ __align__(16) unsigned short Bh[128 * 32];
    __shared__ __align__(16) unsigned short Bl[128 * 32];   // mode 0 only

    const int t    = threadIdx.x;
    const int lane = t & 63;
    const int s    = lane & 15;
    const int row0 = blockIdx.x * 128;
    const int col0 = blockIdx.y * 128;
    const int m0   = ((t >> 6) >> 1) * 64;
    const int n0   = ((t >> 6) & 1) * 64;

    floatx4 acc[4][4];
    #pragma unroll
    for (int i = 0; i < 4; ++i)
        #pragma unroll
        for (int j = 0; j < 4; ++j)
            acc[i][j] = (floatx4)(0.0f);

    // staging: thread t -> row t>>2 (and +64), LDS chunk t&3, SOURCE chunk xor'd
    const int sr  = t >> 2;
    const int skx = ((t & 3) ^ ((t >> 3) & 3)) * 8;
    char* dA  = (char*)Ah + (size_t)t * 16;
    char* dAl = (char*)Al + (size_t)t * 16;
    char* dB  = (char*)Bh + (size_t)t * 16;
    char* dBl = (char*)Bl + (size_t)t * 16;
    const size_t arow = (size_t)(row0 + sr) * 2048 + skx;
    const size_t brow = (size_t)(col0 + sr) * 2048 + skx;

    #define ISSUE(k0)                                                                         \
    {                                                                                         \
        const unsigned short* ga = Ap + arow + (k0);                                          \
        const unsigned short* gb = Bp + brow + (k0);                                          \
        __builtin_amdgcn_global_load_lds((gvoid*)ga,                 (lvoid*)dA,          16, 0, 0); \
        __builtin_amdgcn_global_load_lds((gvoid*)(ga + 64*2048),     (lvoid*)(dA + 4096), 16, 0, 0); \
        __builtin_amdgcn_global_load_lds((gvoid*)(ga + 1024),        (lvoid*)dAl,         16, 0, 0); \
        __builtin_amdgcn_global_load_lds((gvoid*)(ga + 1024+64*2048),(lvoid*)(dAl + 4096),16, 0, 0); \
        __builtin_amdgcn_global_load_lds((gvoid*)gb,                 (lvoid*)dB,          16, 0, 0); \
        __builtin_amdgcn_global_load_lds((gvoid*)(gb + 64*2048),     (lvoid*)(dB + 4096), 16, 0, 0); \
        if (mode == 0) {                                                                      \
            __builtin_amdgcn_global_load_lds((gvoid*)(gb + 1024),        (lvoid*)dBl,          16, 0, 0); \
            __builtin_amdgcn_global_load_lds((gvoid*)(gb + 1024+64*2048),(lvoid*)(dBl + 4096), 16, 0, 0); \
        }                                                                                     \
    }

    // reader chunk offset: global chunk g lives at LDS chunk g ^ ((s>>1)&3)
    const int cofs = (((lane >> 4) ^ ((lane >> 1) & 3)) << 3);

    ISSUE(0);
    for (int ks = 0; ks < 32; ++ks) {
        __syncthreads();
        short8 ahf[4], alf[4], bhf[4], blf[4];
        #pragma unroll
        for (int i = 0; i < 4; ++i) {
            int ra = (m0 + i * 16 + s) * 32 + cofs;
            ahf[i] = *(const short8*)&Ah[ra];
            alf[i] = *(const short8*)&Al[ra];
        }
        #pragma unroll
        for (int j = 0; j < 4; ++j) {
            int rb = (n0 + j * 16 + s) * 32 + cofs;
            bhf[j] = *(const short8*)&Bh[rb];
            if (mode == 0) blf[j] = *(const short8*)&Bl[rb];
        }
        #pragma unroll
        for (int i = 0; i < 4; ++i)
            #pragma unroll
            for (int j = 0; j < 4; ++j) {
                acc[i][j] = __builtin_amdgcn_mfma_f32_16x16x32_bf16(ahf[i], bhf[j], acc[i][j], 0, 0, 0);
                acc[i][j] = __builtin_amdgcn_mfma_f32_16x16x32_bf16(alf[i], bhf[j], acc[i][j], 0, 0, 0);
            }
        if (mode == 0) {
            #pragma unroll
            for (int i = 0; i < 4; ++i)
                #pragma unroll
                for (int j = 0; j < 4; ++j)
                    acc[i][j] = __builtin_amdgcn_mfma_f32_16x16x32_bf16(ahf[i], blf[j], acc[i][j], 0, 0, 0);
        }
        __syncthreads();
        if (ks + 1 < 32) ISSUE((ks + 1) * 32);
    }
    #undef ISSUE

    const int cr = (lane >> 4) * 4;
    const int cc = lane & 15;

    if (mode == 0) {
        #pragma unroll
        for (int i = 0; i < 4; ++i)
            #pragma unroll
            for (int j = 0; j < 4; ++j) {
                int r = row0 + m0 + i * 16 + cr;
                int c = col0 + n0 + j * 16 + cc;
                #pragma unroll
                for (int rr = 0; rr < 4; ++rr)
                    Cf[(size_t)(r + rr) * 1024 + c] = acc[i][j][rr];
            }
        return;
    }

    // ---- mode 1 epilogue: fused RoPE (+1/64 on q,q2), head-major scatter ----
    const int p = col0 >> 10;                   // 0=q 1=k 2=q2 3=k2 4=v (uniform/block)
    const int h = ((col0 + n0) >> 6) & 15;

    if (p < 4) {
        const float sc = (p == 0 || p == 2) ? 0.015625f : 1.0f;
        const float L  = -0.43321698784996581f; // -ln(10000)/32... (log2 scale below)
        // inv_freq = 10000^(-d/32) = exp2(-d * log2(10000)/32)
        const float L2 = -0.41524101186092029f;
        (void)L;
        float inv0 = exp2f((float)cc * L2);
        float inv1 = exp2f((float)(16 + cc) * L2);
        #pragma unroll
        for (int i = 0; i < 4; ++i) {
            #pragma unroll
            for (int rr = 0; rr < 4; ++rr) {
                int r = row0 + m0 + i * 16 + cr + rr;
                float tt = (float)(r & 2047);
                float s0, c0, s1, c1;
                __sincosf(tt * inv0, &s0, &c0);
                __sincosf(tt * inv1, &s1, &c1);
                float x1, x2;
                x1 = acc[i][0][rr]; x2 = acc[i][2][rr];
                acc[i][0][rr] = (x1 * c0 + x2 * s0) * sc;
                acc[i][2][rr] = (x2 * c0 - x1 * s0) * sc;
                x1 = acc[i][1][rr]; x2 = acc[i][3][rr];
                acc[i][1][rr] = (x1 * c1 + x2 * s1) * sc;
                acc[i][3][rr] = (x2 * c1 - x1 * s1) * sc;
            }
        }
        unsigned short* hp = Ch + (size_t)p * 4194304;
        #pragma unroll
        for (int i = 0; i < 4; ++i) {
            int r0  = row0 + m0 + i * 16 + cr;
            int bhi = ((r0 >> 11) << 4) + h;
            size_t base = ((size_t)bhi * 2048 + (r0 & 2047)) * 64;
            #pragma unroll
            for (int j = 0; j < 4; ++j) {
                int d = (n0 + j * 16 + cc) & 63;
                #pragma unroll
                for (int rr = 0; rr < 4; ++rr)
                    hp[base + (size_t)rr * 64 + d] = f2bf(acc[i][j][rr]);
            }
        }
    } else {
        // v: store transposed Vt[bh][d][t], b64 along t
        #pragma unroll
        for (int i = 0; i < 4; ++i) {
            int r0  = row0 + m0 + i * 16 + cr;
            int bhi = ((r0 >> 11) << 4) + h;
            #pragma unroll
            for (int j = 0; j < 4; ++j) {
                int d = (n0 + j * 16 + cc) & 63;
                ushort4 o;
                o.x = f2bf(acc[i][j][0]); o.y = f2bf(acc[i][j][1]);
                o.z = f2bf(acc[i][j][2]); o.w = f2bf(acc[i][j][3]);
                *(ushort4*)(Vt + ((size_t)bhi * 64 + d) * 2048 + (r0 & 2047)) = o;
            }
        }
    }
}

// ---------------------------------------------------------------------------
// MFMA bilinear causal attention, S-transposed formulation.
// Block=(qt-tile 128, bh), 4 waves. S_T = K.Q^T (C-frag rows = k contiguous)
// => P stored b64 into psq[q][k] (overlays ks/k2s, dead after S-phase),
// PV reads psq b128 as standard 16x16x32 A-frags. LDS = 80 KB -> 2 blocks/CU.
// ---------------------------------------------------------------------------
__global__ __launch_bounds__(256, 2)
void attn_mfma(const unsigned short* __restrict__ qh, const unsigned short* __restrict__ q2h,
               const unsigned short* __restrict__ kh, const unsigned short* __restrict__ k2h,
               const unsigned short* __restrict__ vt, unsigned short* __restrict__ zout)
{
    __shared__ __align__(16) unsigned short smem[40960];   // 80 KB
    unsigned short* qs  = smem;              // [128][64] rot8
    unsigned short* q2s = smem + 8192;
    unsigned short* ks  = smem + 16384;      // [128][64] rot8
    unsigned short* k2s = smem + 24576;
    unsigned short* vts = smem + 32768;      // [64][128] rot16
    unsigned short* psq = smem + 16384;      // [128][128] rot16, overlays ks/k2s

    const int bh = blockIdx.y;
    const int qt = (bh < 16) ? (15 - blockIdx.x) : blockIdx.x;  // pair heavy+light per CU
    const int t  = threadIdx.x;
    const int lane = t & 63;
    const int w    = t >> 6;
    const int s    = lane & 15;
    const int g    = lane >> 4;
    const int m0   = (w >> 1) * 64;   // k-split
    const int n0   = (w & 1) * 64;    // q-split

    // ---- stage q, q2 (once) ----
    {
        const unsigned short* qb  = qh  + ((size_t)bh * 2048 + qt * 128) * 64;
        const unsigned short* q2b = q2h + ((size_t)bh * 2048 + qt * 128) * 64;
        const int row = t >> 1;
        #pragma unroll
        for (int c = 0; c < 4; ++c) {
            int cg  = (t & 1) * 4 + c;
            short8 a  = *(const short8*)(qb  + (size_t)row * 64 + cg * 8);
            short8 a2 = *(const short8*)(q2b + (size_t)row * 64 + cg * 8);
            int cgm = (cg + row) & 7;
            *(short8*)&qs [row * 64 + cgm * 8] = a;
            *(short8*)&q2s[row * 64 + cgm * 8] = a2;
        }
    }

    floatx4 zac[2][4];
    #pragma unroll
    for (int i = 0; i < 2; ++i)
        #pragma unroll
        for (int j = 0; j < 4; ++j)
            zac[i][j] = (floatx4)(0.0f);

    for (int tk = 0; tk <= qt; ++tk) {
        // ---- register prefetch ----
        short8 kf[4], k2f[4], vf[4];
        {
            const unsigned short* kb  = kh  + ((size_t)bh * 2048 + tk * 128) * 64;
            const unsigned short* k2b = k2h + ((size_t)bh * 2048 + tk * 128) * 64;
            const unsigned short* vb  = vt  + (size_t)bh * 131072 + tk * 128;
            const int krow = t >> 1;
            const int vd   = t >> 2;
            #pragma unroll
            for (int c = 0; c < 4; ++c) {
                int cg = (t & 1) * 4 + c;
                kf[c]  = *(const short8*)(kb  + (size_t)krow * 64 + cg * 8);
                k2f[c] = *(const short8*)(k2b + (size_t)krow * 64 + cg * 8);
                int cg16 = 4 * (t & 3) + c;
                vf[c]  = *(const short8*)(vb + (size_t)vd * 2048 + cg16 * 8);
            }
        }
        __syncthreads();   // b0: prev PV done reading psq(=ks region)/vts
        {
            const int krow = t >> 1;
            const int vd   = t >> 2;
            #pragma unroll
            for (int c = 0; c < 4; ++c) {
                int cg  = (t & 1) * 4 + c;
                int cgm = (cg + krow) & 7;
                *(short8*)&ks [krow * 64 + cgm * 8] = kf[c];
                *(short8*)&k2s[krow * 64 + cgm * 8] = k2f[c];
                int cg16  = 4 * (t & 3) + c;
                int cgm16 = (cg16 + vd) & 15;
                *(short8*)&vts[vd * 128 + cgm16 * 8] = vf[c];
            }
        }
        __syncthreads();   // b1: tiles visible

        // ---- S phase (transposed): A = k-rows, B = q-rows ----
        floatx4 a1[4][4], a2[4][4];
        #pragma unroll
        for (int i = 0; i < 4; ++i)
            #pragma unroll
            for (int j = 0; j < 4; ++j) { a1[i][j] = (floatx4)(0.0f); a2[i][j] = (floatx4)(0.0f); }

        #pragma unroll
        for (int kstep = 0; kstep < 2; ++kstep) {
            const int gl = kstep * 4 + g;
            short8 ak[4], ak2[4], bq[4], bq2[4];
            #pragma unroll
            for (int i = 0; i < 4; ++i) {
                int row = m0 + i * 16 + s;
                int a = row * 64 + ((gl + row) & 7) * 8;
                ak[i]  = *(const short8*)&ks [a];
                ak2[i] = *(const short8*)&k2s[a];
            }
            #pragma unroll
            for (int j = 0; j < 4; ++j) {
                int row = n0 + j * 16 + s;
                int a = row * 64 + ((gl + row) & 7) * 8;
                bq[j]  = *(const short8*)&qs [a];
                bq2[j] = *(const short8*)&q2s[a];
            }
            #pragma unroll
            for (int i = 0; i < 4; ++i)
                #pragma unroll
                for (int j = 0; j < 4; ++j) {
                    a1[i][j] = __builtin_amdgcn_mfma_f32_16x16x32_bf16(ak[i],  bq[j],  a1[i][j], 0, 0, 0);
                    a2[i][j] = __builtin_amdgcn_mfma_f32_16x16x32_bf16(ak2[i], bq2[j], a2[i][j], 0, 0, 0);
                }
        }

        __syncthreads();   // b2: all S reads of ks/k2s done; safe to overwrite as psq

        // ---- P = S1*S2 -> psq[q][k], b64 writes (rows k contiguous per frag) ----
        if (tk < qt) {
            #pragma unroll
            for (int i = 0; i < 4; ++i) {
                const int kl0   = m0 + i * 16 + g * 4;
                const int chunk = kl0 >> 3;
                const int sub   = kl0 & 7;
                #pragma unroll
                for (int j = 0; j < 4; ++j) {
                    const int ql = n0 + j * 16 + s;
                    ushort4 pw;
                    pw.x = f2bf(a1[i][j][0] * a2[i][j][0]);
                    pw.y = f2bf(a1[i][j][1] * a2[i][j][1]);
                    pw.z = f2bf(a1[i][j][2] * a2[i][j][2]);
                    pw.w = f2bf(a1[i][j][3] * a2[i][j][3]);
                    *(ushort4*)&psq[ql * 128 + ((chunk + ql) & 15) * 8 + sub] = pw;
                }
            }
        } else {
            #pragma unroll
            for (int i = 0; i < 4; ++i) {
                const int kl0   = m0 + i * 16 + g * 4;
                const int chunk = kl0 >> 3;
                const int sub   = kl0 & 7;
                #pragma unroll
                for (int j = 0; j < 4; ++j) {
                    const int ql = n0 + j * 16 + s;
                    ushort4 pw;
                    pw.x = (kl0 + 0 <= ql) ? f2bf(a1[i][j][0] * a2[i][j][0]) : (unsigned short)0;
                    pw.y = (kl0 + 1 <= ql) ? f2bf(a1[i][j][1] * a2[i][j][1]) : (unsigned short)0;
                    pw.z = (kl0 + 2 <= ql) ? f2bf(a1[i][j][2] * a2[i][j][2]) : (unsigned short)0;
                    pw.w = (kl0 + 3 <= ql) ? f2bf(a1[i][j][3] * a2[i][j][3]) : (unsigned short)0;
                    *(ushort4*)&psq[ql * 128 + ((chunk + ql) & 15) * 8 + sub] = pw;
                }
            }
        }

        __syncthreads();   // b3: psq visible

        // ---- PV: z[q][d] += P[q][k] * vT[d][k] ----
        const int wm0 = w * 32;
        #pragma unroll
        for (int kstep = 0; kstep < 4; ++kstep) {
            const int cbase = kstep * 4 + g;
            short8 ap[2], bv[4];
            #pragma unroll
            for (int i2 = 0; i2 < 2; ++i2) {
                int q = wm0 + i2 * 16 + s;
                ap[i2] = *(const short8*)&psq[q * 128 + ((cbase + q) & 15) * 8];
            }
            #pragma unroll
            for (int jd = 0; jd < 4; ++jd) {
                int d = jd * 16 + s;
                bv[jd] = *(const short8*)&vts[d * 128 + ((cbase + d) & 15) * 8];
            }
            #pragma unroll
            for (int i2 = 0; i2 < 2; ++i2)
                #pragma unroll
                for (int jd = 0; jd < 4; ++jd)
                    zac[i2][jd] = __builtin_amdgcn_mfma_f32_16x16x32_bf16(ap[i2], bv[jd], zac[i2][jd], 0, 0, 0);
        }
    }

    // ---- epilogue: z -> split bf16 [hi | lo] into zout[4096][2048] ----
    const int b = bh >> 4, h = bh & 15;
    const size_t zrow0 = (size_t)(b * TSEQ + qt * 128);
    #pragma unroll
    for (int i2 = 0; i2 < 2; ++i2)
        #pragma unroll
        for (int j = 0; j < 4; ++j)
            #pragma unroll
            for (int r = 0; r < 4; ++r) {
                float zv = zac[i2][j][r];
                unsigned short hi = f2bf(zv);
                unsigned short lo = f2bf(zv - bf2f(hi));
                size_t row = zrow0 + w * 32 + i2 * 16 + g * 4 + r;
                int col = h * 64 + j * 16 + s;
                zout[row * 2048 + col]        = hi;
                zout[row * 2048 + 1024 + col] = lo;
            }
}

// ---------------------------------------------------------------------------
extern "C" void kernel_launch(void* const* d_in, const int* in_sizes, int n_in,
                              void* d_out, int out_size, void* d_ws, size_t ws_size,
                              hipStream_t stream)
{
    const float* x     = (const float*)d_in[0];
    const float* Wq    = (const float*)d_in[1];
    const float* Wk    = (const float*)d_in[2];
    const float* Wq2   = (const float*)d_in[3];
    const float* Wk2   = (const float*)d_in[4];
    const float* Wv    = (const float*)d_in[5];
    const float* Wproj = (const float*)d_in[6];

    // workspace (bytes):
    //   Xp    bf16 [4096][2048] (x-split, later z-split) @ 0          (16,777,216)
    //   Wp    bf16 [6144][2048]                          @ 16,777,216 (25,165,824)
    //   heads bf16 4x[32][2048][64] (q,k,q2,k2)          @ 41,943,040 (33,554,432)
    //   vt    bf16 [32][64][2048]                        @ 75,497,472 ( 8,388,608)
    //   total 83,886,080
    unsigned short* Xp    = (unsigned short*)d_ws;
    unsigned short* Wp    = (unsigned short*)((char*)d_ws + 16777216);
    unsigned short* heads = (unsigned short*)((char*)d_ws + 41943040);
    unsigned short* vt    = (unsigned short*)((char*)d_ws + 75497472);

    const size_t HS = (size_t)32 * 2048 * 64;
    unsigned short* qh  = heads;
    unsigned short* kh  = heads + 1 * HS;
    unsigned short* q2h = heads + 2 * HS;
    unsigned short* k2h = heads + 3 * HS;

    pack_split_kernel<<<4096, 256, 0, stream>>>(x, Xp);
    pack_split_w6_kernel<<<6144, 256, 0, stream>>>(Wproj, Wq, Wk, Wq2, Wk2, Wv, Wp);
    // qkv GEMM (2-term) + fused RoPE/scale, head-major bf16 out + v transposed
    gemm_split_bf16<<<dim3(32, 40), 256, 0, stream>>>(Xp, Wp + (size_t)1024 * 2048,
                                                      nullptr, heads, vt, 1);
    attn_mfma<<<dim3(16, 32), 256, 0, stream>>>(qh, q2h, kh, k2h, vt, Xp);
    // output projection (3-term, fp32 out)
    gemm_split_bf16<<<dim3(32, 8), 256, 0, stream>>>(Xp, Wp, (float*)d_out, nullptr, nullptr, 0);
}

// Round 6
// 278.124 us; speedup vs baseline: 5.9363x; 1.1587x over previous
//
#include <hip/hip_runtime.h>
#include <hip/hip_bf16.h>

#define TSEQ 2048
#define NHEAD 16
#define DM 1024
#define NBATCH 2
#define MTOK (NBATCH * TSEQ)   // 4096

typedef __attribute__((ext_vector_type(8))) short short8;
typedef __attribute__((ext_vector_type(4))) float floatx4;
typedef __attribute__((address_space(1))) const void gvoid;
typedef __attribute__((address_space(3))) void lvoid;

static __device__ __forceinline__ unsigned short f2bf(float f) {
    unsigned int u = __float_as_uint(f);
    return (unsigned short)((u + 0x7fffu + ((u >> 16) & 1u)) >> 16);
}
static __device__ __forceinline__ float bf2f(unsigned short h) {
    return __uint_as_float(((unsigned int)h) << 16);
}

// ---------------------------------------------------------------------------
// Pack x and the 6 weight matrices to split bf16 [hi(1024)|lo(1024)] rows.
// blocks [0,4096) -> x ; [4096,10240) -> weights (1024 blocks each).
// ---------------------------------------------------------------------------
__global__ __launch_bounds__(256)
void pack_all_kernel(const float* __restrict__ x,
                     const float* __restrict__ w0, const float* __restrict__ w1,
                     const float* __restrict__ w2, const float* __restrict__ w3,
                     const float* __restrict__ w4, const float* __restrict__ w5,
                     unsigned short* __restrict__ dstX, unsigned short* __restrict__ dstW)
{
    const float* src;
    unsigned short* dst;
    int gid;
    if (blockIdx.x < 4096) {
        src = x; dst = dstX;
        gid = blockIdx.x * 256 + threadIdx.x;
    } else {
        int wi = (blockIdx.x - 4096) >> 10;
        const float* srcs[6] = {w0, w1, w2, w3, w4, w5};
        src = srcs[wi];
        dst = dstW + (size_t)wi * 1024 * 2048;
        gid = ((blockIdx.x - 4096) & 1023) * 256 + threadIdx.x;
    }
    int e   = gid * 4;
    int row = e >> 10;
    int col = e & 1023;
    float4 f = *(const float4*)(src + (size_t)row * 1024 + col);
    ushort4 hi, lo;
    hi.x = f2bf(f.x); lo.x = f2bf(f.x - bf2f(hi.x));
    hi.y = f2bf(f.y); lo.y = f2bf(f.y - bf2f(hi.y));
    hi.z = f2bf(f.z); lo.z = f2bf(f.z - bf2f(hi.z));
    hi.w = f2bf(f.w); lo.w = f2bf(f.w - bf2f(hi.w));
    *(ushort4*)(dst + (size_t)row * 2048 + col)        = hi;
    *(ushort4*)(dst + (size_t)row * 2048 + 1024 + col) = lo;
}

// ---------------------------------------------------------------------------
// qkv GEMM: C = (hiA+loA)*hiB^T (2-term), 128x128 tile, BK=32, 24 KB LDS.
// Epilogue fuses RoPE + 1/64 q-scale, scatters bf16 head-major
// heads[p][bh][t][64] (p=q,k,q2,k2) and v transposed Vt[bh][64][2048].
// XOR source-chunk swizzle keeps global_load_lds linear & reads conflict-free.
// ---------------------------------------------------------------------------
__global__ __launch_bounds__(256)
void gemm_qkv(const unsigned short* __restrict__ Ap,
              const unsigned short* __restrict__ Bp,
              unsigned short* __restrict__ Ch, unsigned short* __restrict__ Vt)
{
    __shared__ __align__(16) unsigned short Ah[128 * 32];
    __shared__ __align__(16) unsigned short Al[128 * 32];
    __shared__ __align__(16) unsigned short Bh[128 * 32];

    const int t    = threadIdx.x;
    const int lane = t & 63;
    const int s    = lane & 15;
    const int row0 = blockIdx.x * 128;
    const int col0 = blockIdx.y * 128;
    const int m0   = ((t >> 6) >> 1) * 64;
    const int n0   = ((t >> 6) & 1) * 64;

    floatx4 acc[4][4];
    #pragma unroll
    for (int i = 0; i < 4; ++i)
        #pragma unroll
        for (int j = 0; j < 4; ++j)
            acc[i][j] = (floatx4)(0.0f);

    const int sr  = t >> 2;
    const int skx = ((t & 3) ^ ((t >> 3) & 3)) * 8;
    char* dA  = (char*)Ah + (size_t)t * 16;
    char* dAl = (char*)Al + (size_t)t * 16;
    char* dB  = (char*)Bh + (size_t)t * 16;
    const size_t arow = (size_t)(row0 + sr) * 2048 + skx;
    const size_t brow = (size_t)(col0 + sr) * 2048 + skx;

    #define ISSUE(k0)                                                                         \
    {                                                                                         \
        const unsigned short* ga = Ap + arow + (k0);                                          \
        const unsigned short* gb = Bp + brow + (k0);                                          \
        __builtin_amdgcn_global_load_lds((gvoid*)ga,                 (lvoid*)dA,          16, 0, 0); \
        __builtin_amdgcn_global_load_lds((gvoid*)(ga + 64*2048),     (lvoid*)(dA + 4096), 16, 0, 0); \
        __builtin_amdgcn_global_load_lds((gvoid*)(ga + 1024),        (lvoid*)dAl,         16, 0, 0); \
        __builtin_amdgcn_global_load_lds((gvoid*)(ga + 1024+64*2048),(lvoid*)(dAl + 4096),16, 0, 0); \
        __builtin_amdgcn_global_load_lds((gvoid*)gb,                 (lvoid*)dB,          16, 0, 0); \
        __builtin_amdgcn_global_load_lds((gvoid*)(gb + 64*2048),     (lvoid*)(dB + 4096), 16, 0, 0); \
    }

    const int cofs = (((lane >> 4) ^ ((lane >> 1) & 3)) << 3);

    ISSUE(0);
    for (int ks = 0; ks < 32; ++ks) {
        __syncthreads();
        short8 ahf[4], alf[4], bhf[4];
        #pragma unroll
        for (int i = 0; i < 4; ++i) {
            int ra = (m0 + i * 16 + s) * 32 + cofs;
            ahf[i] = *(const short8*)&Ah[ra];
            alf[i] = *(const short8*)&Al[ra];
        }
        #pragma unroll
        for (int j = 0; j < 4; ++j)
            bhf[j] = *(const short8*)&Bh[(n0 + j * 16 + s) * 32 + cofs];
        #pragma unroll
        for (int i = 0; i < 4; ++i)
            #pragma unroll
            for (int j = 0; j < 4; ++j) {
                acc[i][j] = __builtin_amdgcn_mfma_f32_16x16x32_bf16(ahf[i], bhf[j], acc[i][j], 0, 0, 0);
                acc[i][j] = __builtin_amdgcn_mfma_f32_16x16x32_bf16(alf[i], bhf[j], acc[i][j], 0, 0, 0);
            }
        __syncthreads();
        if (ks + 1 < 32) ISSUE((ks + 1) * 32);
    }
    #undef ISSUE

    const int cr = (lane >> 4) * 4;
    const int cc = lane & 15;
    const int p  = col0 >> 10;                   // 0=q 1=k 2=q2 3=k2 4=v
    const int h  = ((col0 + n0) >> 6) & 15;

    if (p < 4) {
        const float sc = (p == 0 || p == 2) ? 0.015625f : 1.0f;
        const float L2 = -0.41524101186092029f;  // -log2(10000)/32
        float inv0 = exp2f((float)cc * L2);
        float inv1 = exp2f((float)(16 + cc) * L2);
        #pragma unroll
        for (int i = 0; i < 4; ++i) {
            #pragma unroll
            for (int rr = 0; rr < 4; ++rr) {
                int r = row0 + m0 + i * 16 + cr + rr;
                float tt = (float)(r & 2047);
                float s0, c0, s1, c1;
                __sincosf(tt * inv0, &s0, &c0);
                __sincosf(tt * inv1, &s1, &c1);
                float x1, x2;
                x1 = acc[i][0][rr]; x2 = acc[i][2][rr];
                acc[i][0][rr] = (x1 * c0 + x2 * s0) * sc;
                acc[i][2][rr] = (x2 * c0 - x1 * s0) * sc;
                x1 = acc[i][1][rr]; x2 = acc[i][3][rr];
                acc[i][1][rr] = (x1 * c1 + x2 * s1) * sc;
                acc[i][3][rr] = (x2 * c1 - x1 * s1) * sc;
            }
        }
        unsigned short* hp = Ch + (size_t)p * 4194304;
        #pragma unroll
        for (int i = 0; i < 4; ++i) {
            int r0  = row0 + m0 + i * 16 + cr;
            int bhi = ((r0 >> 11) << 4) + h;
            size_t base = ((size_t)bhi * 2048 + (r0 & 2047)) * 64;
            #pragma unroll
            for (int j = 0; j < 4; ++j) {
                int d = (n0 + j * 16 + cc) & 63;
                #pragma unroll
                for (int rr = 0; rr < 4; ++rr)
                    hp[base + (size_t)rr * 64 + d] = f2bf(acc[i][j][rr]);
            }
        }
    } else {
        #pragma unroll
        for (int i = 0; i < 4; ++i) {
            int r0  = row0 + m0 + i * 16 + cr;
            int bhi = ((r0 >> 11) << 4) + h;
            #pragma unroll
            for (int j = 0; j < 4; ++j) {
                int d = (n0 + j * 16 + cc) & 63;
                ushort4 o;
                o.x = f2bf(acc[i][j][0]); o.y = f2bf(acc[i][j][1]);
                o.z = f2bf(acc[i][j][2]); o.w = f2bf(acc[i][j][3]);
                *(ushort4*)(Vt + ((size_t)bhi * 64 + d) * 2048 + (r0 & 2047)) = o;
            }
        }
    }
}

// ---------------------------------------------------------------------------
// Output projection: C = (hiA+loA)*hiB^T + hiA*loB^T (3-term), fp32 out.
// Tile 128x64, grid (32,16)=512 blocks (2/CU), 24 KB LDS, wave-tile 64x32.
// ---------------------------------------------------------------------------
__global__ __launch_bounds__(256)
void gemm_proj(const unsigned short* __restrict__ Ap,
               const unsigned short* __restrict__ Bp,
               float* __restrict__ Cf)
{
    __shared__ __align__(16) unsigned short Ah[128 * 32];
    __shared__ __align__(16) unsigned short Al[128 * 32];
    __shared__ __align__(16) unsigned short Bh[64 * 32];
    __shared__ __align__(16) unsigned short Bl[64 * 32];

    const int t    = threadIdx.x;
    const int lane = t & 63;
    const int s    = lane & 15;
    const int row0 = blockIdx.x * 128;
    const int col0 = blockIdx.y * 64;
    const int m0   = ((t >> 6) >> 1) * 64;
    const int n0   = ((t >> 6) & 1) * 32;

    floatx4 acc[4][2];
    #pragma unroll
    for (int i = 0; i < 4; ++i)
        #pragma unroll
        for (int j = 0; j < 2; ++j)
            acc[i][j] = (floatx4)(0.0f);

    const int sr  = t >> 2;
    const int skx = ((t & 3) ^ ((t >> 3) & 3)) * 8;
    char* dA  = (char*)Ah + (size_t)t * 16;
    char* dAl = (char*)Al + (size_t)t * 16;
    char* dB  = (char*)Bh + (size_t)t * 16;
    char* dBl = (char*)Bl + (size_t)t * 16;
    const size_t arow = (size_t)(row0 + sr) * 2048 + skx;
    const size_t brow = (size_t)(col0 + sr) * 2048 + skx;   // sr in [0,64)

    #define ISSUE(k0)                                                                         \
    {                                                                                         \
        const unsigned short* ga = Ap + arow + (k0);                                          \
        const unsigned short* gb = Bp + brow + (k0);                                          \
        __builtin_amdgcn_global_load_lds((gvoid*)ga,                 (lvoid*)dA,          16, 0, 0); \
        __builtin_amdgcn_global_load_lds((gvoid*)(ga + 64*2048),     (lvoid*)(dA + 4096), 16, 0, 0); \
        __builtin_amdgcn_global_load_lds((gvoid*)(ga + 1024),        (lvoid*)dAl,         16, 0, 0); \
        __builtin_amdgcn_global_load_lds((gvoid*)(ga + 1024+64*2048),(lvoid*)(dAl + 4096),16, 0, 0); \
        __builtin_amdgcn_global_load_lds((gvoid*)gb,                 (lvoid*)dB,          16, 0, 0); \
        __builtin_amdgcn_global_load_lds((gvoid*)(gb + 1024),        (lvoid*)dBl,         16, 0, 0); \
    }

    const int cofs = (((lane >> 4) ^ ((lane >> 1) & 3)) << 3);

    ISSUE(0);
    for (int ks = 0; ks < 32; ++ks) {
        __syncthreads();
        short8 ahf[4], alf[4], bhf[2], blf[2];
        #pragma unroll
        for (int i = 0; i < 4; ++i) {
            int ra = (m0 + i * 16 + s) * 32 + cofs;
            ahf[i] = *(const short8*)&Ah[ra];
            alf[i] = *(const short8*)&Al[ra];
        }
        #pragma unroll
        for (int j = 0; j < 2; ++j) {
            int rb = (n0 + j * 16 + s) * 32 + cofs;
            bhf[j] = *(const short8*)&Bh[rb];
            blf[j] = *(const short8*)&Bl[rb];
        }
        #pragma unroll
        for (int i = 0; i < 4; ++i)
            #pragma unroll
            for (int j = 0; j < 2; ++j) {
                acc[i][j] = __builtin_amdgcn_mfma_f32_16x16x32_bf16(ahf[i], bhf[j], acc[i][j], 0, 0, 0);
                acc[i][j] = __builtin_amdgcn_mfma_f32_16x16x32_bf16(alf[i], bhf[j], acc[i][j], 0, 0, 0);
                acc[i][j] = __builtin_amdgcn_mfma_f32_16x16x32_bf16(ahf[i], blf[j], acc[i][j], 0, 0, 0);
            }
        __syncthreads();
        if (ks + 1 < 32) ISSUE((ks + 1) * 32);
    }
    #undef ISSUE

    const int cr = (lane >> 4) * 4;
    const int cc = lane & 15;
    #pragma unroll
    for (int i = 0; i < 4; ++i)
        #pragma unroll
        for (int j = 0; j < 2; ++j) {
            int r = row0 + m0 + i * 16 + cr;
            int c = col0 + n0 + j * 16 + cc;
            #pragma unroll
            for (int rr = 0; rr < 4; ++rr)
                Cf[(size_t)(r + rr) * 1024 + c] = acc[i][j][rr];
        }
}

// ---------------------------------------------------------------------------
// MFMA bilinear causal attention, S-transposed, q-frags hoisted to registers.
// psq overlays qs/q2s (dead after the one-time q-frag hoist) => 3 barriers/iter.
// LDS 80 KB, 2 blocks/CU.
// ---------------------------------------------------------------------------
__global__ __launch_bounds__(256, 2)
void attn_mfma(const unsigned short* __restrict__ qh, const unsigned short* __restrict__ q2h,
               const unsigned short* __restrict__ kh, const unsigned short* __restrict__ k2h,
               const unsigned short* __restrict__ vt, unsigned short* __restrict__ zout)
{
    __shared__ __align__(16) unsigned short smem[40960];   // 80 KB
    unsigned short* qs  = smem;              // [128][64] rot8 (init only)
    unsigned short* q2s = smem + 8192;
    unsigned short* psq = smem;              // [128][128] rot16, overlays qs/q2s
    unsigned short* ks  = smem + 16384;      // [128][64] rot8
    unsigned short* k2s = smem + 24576;
    unsigned short* vts = smem + 32768;      // [64][128] rot16

    const int bh = blockIdx.y;
    const int qt = (bh < 16) ? (15 - blockIdx.x) : blockIdx.x;  // pair heavy+light
    const int t  = threadIdx.x;
    const int lane = t & 63;
    const int w    = t >> 6;
    const int s    = lane & 15;
    const int g    = lane >> 4;
    const int m0   = (w >> 1) * 64;   // k-split
    const int n0   = (w & 1) * 64;    // q-split

    // ---- stage q, q2 once, then hoist frags to registers ----
    {
        const unsigned short* qb  = qh  + ((size_t)bh * 2048 + qt * 128) * 64;
        const unsigned short* q2b = q2h + ((size_t)bh * 2048 + qt * 128) * 64;
        const int row = t >> 1;
        #pragma unroll
        for (int c = 0; c < 4; ++c) {
            int cg  = (t & 1) * 4 + c;
            short8 a  = *(const short8*)(qb  + (size_t)row * 64 + cg * 8);
            short8 a2 = *(const short8*)(q2b + (size_t)row * 64 + cg * 8);
            int cgm = (cg + row) & 7;
            *(short8*)&qs [row * 64 + cgm * 8] = a;
            *(short8*)&q2s[row * 64 + cgm * 8] = a2;
        }
    }
    __syncthreads();
    short8 bq[2][4], bq2[2][4];
    #pragma unroll
    for (int kstep = 0; kstep < 2; ++kstep) {
        const int gl = kstep * 4 + g;
        #pragma unroll
        for (int j = 0; j < 4; ++j) {
            int row = n0 + j * 16 + s;
            int a = row * 64 + ((gl + row) & 7) * 8;
            bq[kstep][j]  = *(const short8*)&qs [a];
            bq2[kstep][j] = *(const short8*)&q2s[a];
        }
    }

    floatx4 zac[2][4];
    #pragma unroll
    for (int i = 0; i < 2; ++i)
        #pragma unroll
        for (int j = 0; j < 4; ++j)
            zac[i][j] = (floatx4)(0.0f);

    for (int tk = 0; tk <= qt; ++tk) {
        // ---- register prefetch ----
        short8 kf[4], k2f[4], vf[4];
        {
            const unsigned short* kb  = kh  + ((size_t)bh * 2048 + tk * 128) * 64;
            const unsigned short* k2b = k2h + ((size_t)bh * 2048 + tk * 128) * 64;
            const unsigned short* vb  = vt  + (size_t)bh * 131072 + tk * 128;
            const int krow = t >> 1;
            const int vd   = t >> 2;
            #pragma unroll
            for (int c = 0; c < 4; ++c) {
                int cg = (t & 1) * 4 + c;
                kf[c]  = *(const short8*)(kb  + (size_t)krow * 64 + cg * 8);
                k2f[c] = *(const short8*)(k2b + (size_t)krow * 64 + cg * 8);
                int cg16 = 4 * (t & 3) + c;
                vf[c]  = *(const short8*)(vb + (size_t)vd * 2048 + cg16 * 8);
            }
        }
        __syncthreads();   // b0: prev PV done (psq/vts); prev S done (ks/k2s); q-hoist done
        {
            const int krow = t >> 1;
            const int vd   = t >> 2;
            #pragma unroll
            for (int c = 0; c < 4; ++c) {
                int cg  = (t & 1) * 4 + c;
                int cgm = (cg + krow) & 7;
                *(short8*)&ks [krow * 64 + cgm * 8] = kf[c];
                *(short8*)&k2s[krow * 64 + cgm * 8] = k2f[c];
                int cg16  = 4 * (t & 3) + c;
                int cgm16 = (cg16 + vd) & 15;
                *(short8*)&vts[vd * 128 + cgm16 * 8] = vf[c];
            }
        }
        __syncthreads();   // b1: tiles visible

        // ---- S + P, i-outer (a1/a2 footprint = one i at a time) ----
        #pragma unroll
        for (int i = 0; i < 4; ++i) {
            floatx4 a1[4], a2[4];
            #pragma unroll
            for (int j = 0; j < 4; ++j) { a1[j] = (floatx4)(0.0f); a2[j] = (floatx4)(0.0f); }
            #pragma unroll
            for (int kstep = 0; kstep < 2; ++kstep) {
                const int gl = kstep * 4 + g;
                int row = m0 + i * 16 + s;
                int a = row * 64 + ((gl + row) & 7) * 8;
                short8 ak  = *(const short8*)&ks [a];
                short8 ak2 = *(const short8*)&k2s[a];
                #pragma unroll
                for (int j = 0; j < 4; ++j) {
                    a1[j] = __builtin_amdgcn_mfma_f32_16x16x32_bf16(ak,  bq[kstep][j],  a1[j], 0, 0, 0);
                    a2[j] = __builtin_amdgcn_mfma_f32_16x16x32_bf16(ak2, bq2[kstep][j], a2[j], 0, 0, 0);
                }
            }
            // P-write for this i: psq region unread by anyone during the loop
            const int kl0   = m0 + i * 16 + g * 4;
            const int chunk = kl0 >> 3;
            const int sub   = kl0 & 7;
            if (tk < qt) {
                #pragma unroll
                for (int j = 0; j < 4; ++j) {
                    const int ql = n0 + j * 16 + s;
                    ushort4 pw;
                    pw.x = f2bf(a1[j][0] * a2[j][0]);
                    pw.y = f2bf(a1[j][1] * a2[j][1]);
                    pw.z = f2bf(a1[j][2] * a2[j][2]);
                    pw.w = f2bf(a1[j][3] * a2[j][3]);
                    *(ushort4*)&psq[ql * 128 + ((chunk + ql) & 15) * 8 + sub] = pw;
                }
            } else {
                #pragma unroll
                for (int j = 0; j < 4; ++j) {
                    const int ql = n0 + j * 16 + s;
                    ushort4 pw;
                    pw.x = (kl0 + 0 <= ql) ? f2bf(a1[j][0] * a2[j][0]) : (unsigned short)0;
                    pw.y = (kl0 + 1 <= ql) ? f2bf(a1[j][1] * a2[j][1]) : (unsigned short)0;
                    pw.z = (kl0 + 2 <= ql) ? f2bf(a1[j][2] * a2[j][2]) : (unsigned short)0;
                    pw.w = (kl0 + 3 <= ql) ? f2bf(a1[j][3] * a2[j][3]) : (unsigned short)0;
                    *(ushort4*)&psq[ql * 128 + ((chunk + ql) & 15) * 8 + sub] = pw;
                }
            }
        }

        __syncthreads();   // b2: psq visible

        // ---- PV: z[q][d] += P[q][k] * vT[d][k] ----
        const int wm0 = w * 32;
        #pragma unroll
        for (int kstep = 0; kstep < 4; ++kstep) {
            const int cbase = kstep * 4 + g;
            short8 ap[2], bv[4];
            #pragma unroll
            for (int i2 = 0; i2 < 2; ++i2) {
                int q = wm0 + i2 * 16 + s;
                ap[i2] = *(const short8*)&psq[q * 128 + ((cbase + q) & 15) * 8];
            }
            #pragma unroll
            for (int jd = 0; jd < 4; ++jd) {
                int d = jd * 16 + s;
                bv[jd] = *(const short8*)&vts[d * 128 + ((cbase + d) & 15) * 8];
            }
            #pragma unroll
            for (int i2 = 0; i2 < 2; ++i2)
                #pragma unroll
                for (int jd = 0; jd < 4; ++jd)
                    zac[i2][jd] = __builtin_amdgcn_mfma_f32_16x16x32_bf16(ap[i2], bv[jd], zac[i2][jd], 0, 0, 0);
        }
    }

    // ---- epilogue: z -> split bf16 [hi | lo] into zout[4096][2048] ----
    const int b = bh >> 4, h = bh & 15;
    const size_t zrow0 = (size_t)(b * TSEQ + qt * 128);
    #pragma unroll
    for (int i2 = 0; i2 < 2; ++i2)
        #pragma unroll
        for (int j = 0; j < 4; ++j)
            #pragma unroll
            for (int r = 0; r < 4; ++r) {
                float zv = zac[i2][j][r];
                unsigned short hi = f2bf(zv);
                unsigned short lo = f2bf(zv - bf2f(hi));
                size_t row = zrow0 + w * 32 + i2 * 16 + g * 4 + r;
                int col = h * 64 + j * 16 + s;
                zout[row * 2048 + col]        = hi;
                zout[row * 2048 + 1024 + col] = lo;
            }
}

// ---------------------------------------------------------------------------
extern "C" void kernel_launch(void* const* d_in, const int* in_sizes, int n_in,
                              void* d_out, int out_size, void* d_ws, size_t ws_size,
                              hipStream_t stream)
{
    const float* x     = (const float*)d_in[0];
    const float* Wq    = (const float*)d_in[1];
    const float* Wk    = (const float*)d_in[2];
    const float* Wq2   = (const float*)d_in[3];
    const float* Wk2   = (const float*)d_in[4];
    const float* Wv    = (const float*)d_in[5];
    const float* Wproj = (const float*)d_in[6];

    // workspace (bytes):
    //   Xp    bf16 [4096][2048] (x-split, later z-split) @ 0          (16,777,216)
    //   Wp    bf16 [6144][2048]                          @ 16,777,216 (25,165,824)
    //   heads bf16 4x[32][2048][64] (q,k,q2,k2)          @ 41,943,040 (33,554,432)
    //   vt    bf16 [32][64][2048]                        @ 75,497,472 ( 8,388,608)
    unsigned short* Xp    = (unsigned short*)d_ws;
    unsigned short* Wp    = (unsigned short*)((char*)d_ws + 16777216);
    unsigned short* heads = (unsigned short*)((char*)d_ws + 41943040);
    unsigned short* vt    = (unsigned short*)((char*)d_ws + 75497472);

    const size_t HS = (size_t)32 * 2048 * 64;
    unsigned short* qh  = heads;
    unsigned short* kh  = heads + 1 * HS;
    unsigned short* q2h = heads + 2 * HS;
    unsigned short* k2h = heads + 3 * HS;

    pack_all_kernel<<<10240, 256, 0, stream>>>(x, Wproj, Wq, Wk, Wq2, Wk2, Wv, Xp, Wp);
    gemm_qkv<<<dim3(32, 40), 256, 0, stream>>>(Xp, Wp + (size_t)1024 * 2048, heads, vt);
    attn_mfma<<<dim3(16, 32), 256, 0, stream>>>(qh, q2h, kh, k2h, vt, Xp);
    gemm_proj<<<dim3(32, 16), 256, 0, stream>>>(Xp, Wp, (float*)d_out);
}